// Round 11
// baseline (914.139 us; speedup 1.0000x reference)
//
#include <hip/hip_runtime.h>
#include <math.h>

typedef unsigned short bf16_t;
typedef __attribute__((ext_vector_type(8))) short short8;
typedef __attribute__((ext_vector_type(4))) float f32x4;

#define B_ 4
#define C_ 128
#define H_ 128
#define W_ 128
#define L_ (H_*W_)               // 16384
#define NS  ((size_t)B_*L_*C_)   // 8388608 elems
#define NH  ((size_t)B_*L_*64)
#define NSP ((size_t)L_*C_)
#define PI_F 3.14159265358979323846f
#define BN_INV 0.9999950000374997f   // (1+1e-5)^-0.5
#define THETA_SC 0.8304820237218406f // log2(10000)/16
#define TOTW 157148
#define W16SHIFT 107548              // offsets >= this get +4 in bf16 mirror (8-align po_w/red_w)
#define WOFF_PO 107612
#define WOFF_RED 123996

// half-spectrum geometry: cols v=0..64 stored, padded to 66 (col 65 = 0)
#define W2_ 66
#define L2_ (128*W2_)            // 8448 per channel plane

__device__ __forceinline__ float ldf(bf16_t v){ return __uint_as_float(((unsigned)v)<<16); }
__device__ __forceinline__ bf16_t f2b(float f){
  unsigned u = __float_as_uint(f);
  u += 0x7fffu + ((u>>16)&1u);     // RNE
  return (bf16_t)(u>>16);
}

// workspace layout
#define WGSLOT ((size_t)B_*8*L_)
#define ACCSZ 2304
#define CWSZ 157184                  // fp32 weights
#define CW16SZF 78592                // bf16 mirror in floats
#define WSF (6*NS + 3*NH + WGSLOT + ACCSZ + CWSZ + CW16SZF + 16)
__device__ float g_ws[WSF];

// ---------------------------------------------------------------- dtype probe + weight convert
__global__ void k_probe(const bf16_t* __restrict__ xb, int* __restrict__ flag){
  __shared__ int vote;
  if (threadIdx.x == 0) vote = 0;
  __syncthreads();
  int bad = 0;
  for (int i = threadIdx.x; i < 2048; i += 256) {
    float v = ldf(xb[2*i]);
    if (!(fabsf(v) < 1e6f)) bad = 1;
  }
  if (bad) atomicOr(&vote, 1);
  __syncthreads();
  if (threadIdx.x == 0) *flag = vote;  // 1 = fp32 storage, 0 = bf16 storage
}

struct P47 { const void* p[47]; };
__device__ __constant__ int c_wsz[47] = {
  16384,128,128,128,1152,128,1024,8,8,8,1024,128,128,128,128,128,
  16384,128,1152,16384,128,3200,16384,128,4096,64,576,64,8192,128,
  576,64,16384,128,1152,128,128,128,512,4,512,128,16384,32768,128,128,128};

__global__ __launch_bounds__(256) void k_cvt(P47 ps, const int* __restrict__ flagp,
                                             float* __restrict__ dst){
  int g = blockIdx.x*256 + threadIdx.x;
  if (g >= TOTW) return;
  int fl = *flagp;
  int idx = 0, off = g;
  while (off >= c_wsz[idx]) { off -= c_wsz[idx]; idx++; }
  const void* s = ps.p[idx];
  dst[g] = fl ? ((const float*)s)[off] : ldf(((const bf16_t*)s)[off]);
}

__global__ __launch_bounds__(256) void k_cvt16(const float* __restrict__ src, bf16_t* __restrict__ dst){
  int g = blockIdx.x*256 + threadIdx.x;
  if (g >= TOTW) return;
  dst[g + (g >= W16SHIFT ? 4 : 0)] = f2b(src[g]);
}

// fold po into red: red_w[:,128+in] <- sum_j red_w[:,128+j] * po_w[j][in]
__global__ __launch_bounds__(256) void k_fuse_red(const float* __restrict__ po,
    const float* __restrict__ rw, bf16_t* __restrict__ dst16){
  int g = blockIdx.x*256 + threadIdx.x;   // o*128 + in, 16384 total
  int o = g >> 7, in = g & 127;
  float acc = 0.f;
  for (int j = 0; j < 128; j++) acc += rw[o*256 + 128 + j] * po[j*128 + in];
  dst16[o*256 + 128 + in] = f2b(acc);
}

__global__ void k_zero(float* p, int n){
  int i = blockIdx.x*256 + threadIdx.x;
  if (i < n) p[i] = 0.f;
}

// ---------------------------------------------------------------- FFT core (hoisted twiddles)
__device__ __forceinline__ void tw_fwd(int lane, float* tc, float* ts) {
  sincosf(-PI_F * (float)lane * (1.f/64.f), &ts[0], &tc[0]);
  int i = 1;
  #pragma unroll
  for (int m = 32; m >= 1; m >>= 1, i++) {
    int k = lane & (m-1);
    sincosf(-PI_F * (float)k / (float)m, &ts[i], &tc[i]);
  }
}
__device__ __forceinline__ void tw_inv(int lane, float* tc, float* ts) {
  int i = 0;
  #pragma unroll
  for (int m = 1; m <= 32; m <<= 1, i++) {
    int k = lane & (m-1);
    sincosf(PI_F * (float)k / (float)m, &ts[i], &tc[i]);
  }
  sincosf(PI_F * (float)lane * (1.f/64.f), &ts[6], &tc[6]);
}

// DIF network: output lo[p] = X(2*br6(p)), hi[p] = X(2*br6(p)+1)
__device__ __forceinline__ void fft128_fwd(float& lor, float& loi, float& hir, float& hii,
                                           int lane, const float* tc, const float* ts) {
  {
    float s = ts[0], c = tc[0];
    float ar = lor, ai = loi;
    float dr = ar - hir, di = ai - hii;
    lor = ar + hir; loi = ai + hii;
    hir = dr*c - di*s; hii = dr*s + di*c;
  }
  int i = 1;
  #pragma unroll
  for (int m = 32; m >= 1; m >>= 1, i++) {
    float s = ts[i], c = tc[i];
    bool up = (lane & m) != 0;
    {
      float orr = __shfl_xor(lor, m), oii = __shfl_xor(loi, m);
      float sr = lor + orr, si = loi + oii;
      float dr = orr - lor, di = oii - loi;
      float tr = dr*c - di*s, ti = dr*s + di*c;
      lor = up ? tr : sr; loi = up ? ti : si;
    }
    {
      float orr = __shfl_xor(hir, m), oii = __shfl_xor(hii, m);
      float sr = hir + orr, si = hii + oii;
      float dr = orr - hir, di = oii - hii;
      float tr = dr*c - di*s, ti = dr*s + di*c;
      hir = up ? tr : sr; hii = up ? ti : si;
    }
  }
}

// DIT network: input lo[p] = W(2*br6(p)), hi[p] = W(2*br6(p)+1); output natural n
__device__ __forceinline__ void fft128_inv(float& lor, float& loi, float& hir, float& hii,
                                           int lane, const float* tc, const float* ts) {
  int i = 0;
  #pragma unroll
  for (int m = 1; m <= 32; m <<= 1, i++) {
    float s = ts[i], c = tc[i];
    bool up = (lane & m) != 0;
    {
      float orr = __shfl_xor(lor, m), oii = __shfl_xor(loi, m);
      float qr = orr*c - oii*s, qi = orr*s + oii*c;
      float lo_r = lor + qr, lo_i = loi + qi;
      float mr = lor*c - loi*s, mi = lor*s + loi*c;
      float up_r = orr - mr, up_i = oii - mi;
      lor = up ? up_r : lo_r; loi = up ? up_i : lo_i;
    }
    {
      float orr = __shfl_xor(hir, m), oii = __shfl_xor(hii, m);
      float qr = orr*c - oii*s, qi = orr*s + oii*c;
      float lo_r = hir + qr, lo_i = hii + qi;
      float mr = hir*c - hii*s, mi = hir*s + hii*c;
      float up_r = orr - mr, up_i = oii - mi;
      hir = up ? up_r : lo_r; hii = up ? up_i : lo_i;
    }
  }
  {
    float s = ts[6], c = tc[6];
    float qr = hir*c - hii*s, qi = hir*s + hii*c;
    float pr = lor, pi = loi;
    lor = pr + qr; loi = pi + qi;
    hir = pr - qr; hii = pi - qi;
  }
}

// fused seq-read + transpose + forward row FFT, 2 real channels packed per complex FFT.
// Spectrum stored in bf16 (packed dword stores for the (even,odd) column pair).
__global__ __launch_bounds__(256) void k_fft_row_fwd_half(
    const float* __restrict__ in, bf16_t* __restrict__ re, bf16_t* __restrict__ im) {
  __shared__ float T[64*130];
  int tid = threadIdx.x;
  int bid = blockIdx.x;
  int ch = (bid & 1) * 64;
  int h  = (bid >> 1) & 127;
  int b  = bid >> 8;
  const float* ip = in + ((size_t)b*L_ + (size_t)h*128)*128 + ch;
  #pragma unroll
  for (int it = 0; it < 8; it++) {
    int idx = it*256 + tid;            // 2048 float4 loads
    int c4 = (idx & 15)*4, w = idx >> 4;
    float4 v = *(const float4*)(ip + (size_t)w*128 + c4);
    T[(c4+0)*130 + w] = v.x;
    T[(c4+1)*130 + w] = v.y;
    T[(c4+2)*130 + w] = v.z;
    T[(c4+3)*130 + w] = v.w;
  }
  __syncthreads();
  int lane = tid & 63, wv = tid >> 6;
  int rb = (int)(__brev((unsigned)lane) >> 26);   // br6
  int pe = (64 - lane) & 63;
  int po = 63 - lane;
  float tc[7], ts[7];
  tw_fwd(lane, tc, ts);
  #pragma unroll
  for (int t = 0; t < 8; t++) {
    int ca = wv*16 + 2*t, cb = ca + 1;
    float lor = T[ca*130 + lane],      loi = T[cb*130 + lane];
    float hir = T[ca*130 + 64 + lane], hii = T[cb*130 + 64 + lane];
    fft128_fwd(lor, loi, hir, hii, lane, tc, ts);
    float er  = __shfl(lor, rb), ei  = __shfl(loi, rb);
    float our = __shfl(hir, rb), oui = __shfl(hii, rb);
    float per = __shfl(er, pe),  pei = __shfl(ei, pe);
    float por = __shfl(our, po), poi = __shfl(oui, po);
    float ae_r = 0.5f*(er + per),  ae_i = 0.5f*(ei - pei);
    float be_r = 0.5f*(ei + pei),  be_i = 0.5f*(per - er);
    float ao_r = 0.5f*(our + por), ao_i = 0.5f*(oui - poi);
    float bo_r = 0.5f*(oui + poi), bo_i = 0.5f*(por - our);
    if (lane == 32) { ao_r = 0.f; ao_i = 0.f; bo_r = 0.f; bo_i = 0.f; } // col 65 pad
    if (lane <= 32) {
      size_t ba = (size_t)(b*128 + ch + ca)*L2_ + (size_t)h*W2_ + 2*lane;
      size_t bb = (size_t)(b*128 + ch + cb)*L2_ + (size_t)h*W2_ + 2*lane;
      *(unsigned*)(re + ba) = (unsigned)f2b(ae_r) | ((unsigned)f2b(ao_r) << 16);
      *(unsigned*)(im + ba) = (unsigned)f2b(ae_i) | ((unsigned)f2b(ao_i) << 16);
      *(unsigned*)(re + bb) = (unsigned)f2b(be_r) | ((unsigned)f2b(bo_r) << 16);
      *(unsigned*)(im + bb) = (unsigned)f2b(be_i) | ((unsigned)f2b(bo_i) << 16);
    }
  }
}

// column FFT over half-spectrum (bf16 storage): 2 blocks per (b,c) image, 33 cols each.
__global__ __launch_bounds__(256) void k_fft_col_fwd_h(bf16_t* __restrict__ re, bf16_t* __restrict__ im) {
  __shared__ float Lre[128][34];
  __shared__ float Lim[128][34];
  int tid = threadIdx.x;
  size_t img = blockIdx.x >> 1;
  int w0 = (blockIdx.x & 1) * 33;
  bf16_t* rp = re + img * (size_t)L2_ + w0;
  bf16_t* ip = im + img * (size_t)L2_ + w0;
  for (int i = tid; i < 4224; i += 256) {
    int h = i / 33, wl = i - h*33;
    Lre[h][wl] = ldf(rp[(size_t)h*W2_ + wl]);
    Lim[h][wl] = ldf(ip[(size_t)h*W2_ + wl]);
  }
  __syncthreads();
  int lane = tid & 63, wv = tid >> 6;
  float tc[7], ts[7];
  tw_fwd(lane, tc, ts);
  for (int col = wv; col < 33; col += 4) {
    float lor = Lre[lane][col], loi = Lim[lane][col];
    float hir = Lre[lane+64][col], hii = Lim[lane+64][col];
    fft128_fwd(lor, loi, hir, hii, lane, tc, ts);
    Lre[lane][col]=lor; Lim[lane][col]=loi;
    Lre[lane+64][col]=hir; Lim[lane+64][col]=hii;
  }
  __syncthreads();
  for (int i = tid; i < 4224; i += 256) {
    int h = i / 33, wl = i - h*33;
    rp[(size_t)h*W2_ + wl] = f2b(Lre[h][wl]);
    ip[(size_t)h*W2_ + wl] = f2b(Lim[h][wl]);
  }
}

// inverse col FFT (half-spectrum, bf16 storage) with sigmoid gating fused into the load phase.
__global__ __launch_bounds__(256) void k_fft_col_inv_scaled_h(
    bf16_t* __restrict__ re, bf16_t* __restrict__ im,
    const float* __restrict__ wg1, const float* __restrict__ fw2,
    const float* __restrict__ fb2) {
  __shared__ float Lre[128][34];
  __shared__ float Lim[128][34];
  __shared__ float w2r[8];
  int tid = threadIdx.x;
  size_t img = blockIdx.x >> 1;
  int c = (int)(img & 127);
  int b = (int)(img >> 7);
  int w0 = (blockIdx.x & 1) * 33;
  if (tid < 8) w2r[tid] = fw2[c*8 + tid];
  float b2 = fb2[c];
  bf16_t* rp = re + img * (size_t)L2_ + w0;
  bf16_t* ip = im + img * (size_t)L2_ + w0;
  const float* wgp = wg1 + (size_t)b*8*L2_ + w0;
  __syncthreads();
  for (int i = tid; i < 4224; i += 256) {
    int h = i / 33, wl = i - h*33;
    size_t p = (size_t)h*W2_ + wl;
    float a = b2;
    #pragma unroll
    for (int o = 0; o < 8; o++) a += w2r[o] * wgp[(size_t)o*L2_ + p];
    float wgt = 1.f/(1.f+expf(-a));
    Lre[h][wl] = ldf(rp[p]) * wgt;
    Lim[h][wl] = ldf(ip[p]) * wgt;
  }
  __syncthreads();
  int lane = tid & 63, wv = tid >> 6;
  float tc[7], ts[7];
  tw_inv(lane, tc, ts);
  for (int col = wv; col < 33; col += 4) {
    float lor = Lre[lane][col], loi = Lim[lane][col];
    float hir = Lre[lane+64][col], hii = Lim[lane+64][col];
    fft128_inv(lor, loi, hir, hii, lane, tc, ts);
    Lre[lane][col]=lor*(1.f/128.f); Lim[lane][col]=loi*(1.f/128.f);
    Lre[lane+64][col]=hir*(1.f/128.f); Lim[lane+64][col]=hii*(1.f/128.f);
  }
  __syncthreads();
  for (int i = tid; i < 4224; i += 256) {
    int h = i / 33, wl = i - h*33;
    rp[(size_t)h*W2_ + wl] = f2b(Lre[h][wl]);
    ip[(size_t)h*W2_ + wl] = f2b(Lim[h][wl]);
  }
}

// inverse row FFT from half-spectrum (bf16 storage; 2 real channels per complex IFFT)
// + abs+bn+relu + transpose to seq with two fused residual adds. out may alias add1.
__global__ __launch_bounds__(256) void k_fft_row_inv_abs_seq_h(
    const bf16_t* __restrict__ re, const bf16_t* __restrict__ im,
    const float* __restrict__ ng, const float* __restrict__ nbe,
    const float* __restrict__ add1, const float* __restrict__ add2,
    float* __restrict__ out) {
  __shared__ float S[64*132];   // phase A/B: spectra ; phase C/D: T[64*130]
  int tid = threadIdx.x;
  int bid = blockIdx.x;
  int ch = (bid & 1) * 64;
  int h  = (bid >> 1) & 127;
  int b  = bid >> 8;
  {
    const bf16_t* rbase = re + (size_t)(b*128 + ch)*L2_ + (size_t)h*W2_;
    const bf16_t* ibase = im + (size_t)(b*128 + ch)*L2_ + (size_t)h*W2_;
    for (int i = tid; i < 64*66; i += 256) {
      int c = i / 66, v = i - c*66;
      S[c*132 + v]      = ldf(rbase[(size_t)c*L2_ + v]);
      S[c*132 + 66 + v] = ldf(ibase[(size_t)c*L2_ + v]);
    }
  }
  __syncthreads();
  int lane = tid & 63, wv = tid >> 6;
  int rb = (int)(__brev((unsigned)lane) >> 26);
  int vlo = 2*rb, vhi = vlo + 1;
  float tc[7], ts[7];
  tw_inv(lane, tc, ts);
  float rr[8][4];
  #pragma unroll
  for (int t = 0; t < 8; t++) {
    int ca = wv*16 + 2*t, cb = ca + 1;
    const float* Sa = S + ca*132;
    const float* Sb = S + cb*132;
    float lor, loi, hir, hii;
    if (vlo <= 64) {
      float ar = Sa[vlo], ai = Sa[66+vlo], br = Sb[vlo], bi = Sb[66+vlo];
      lor = ar - bi; loi = ai + br;
    } else {
      int u = 128 - vlo;
      float ar = Sa[u], ai = Sa[66+u], br = Sb[u], bi = Sb[66+u];
      lor = ar + bi; loi = br - ai;
    }
    if (vhi <= 64) {
      float ar = Sa[vhi], ai = Sa[66+vhi], br = Sb[vhi], bi = Sb[66+vhi];
      hir = ar - bi; hii = ai + br;
    } else {
      int u = 128 - vhi;
      float ar = Sa[u], ai = Sa[66+u], br = Sb[u], bi = Sb[66+u];
      hir = ar + bi; hii = br - ai;
    }
    fft128_inv(lor, loi, hir, hii, lane, tc, ts);
    rr[t][0] = fabsf(lor);
    rr[t][1] = fabsf(loi);
    rr[t][2] = fabsf(hir);
    rr[t][3] = fabsf(hii);
  }
  __syncthreads();
  float* T = S;
  #pragma unroll
  for (int t = 0; t < 8; t++) {
    int ca = wv*16 + 2*t, cb = ca + 1;
    float sga = ng[ch+ca]*BN_INV, sba = nbe[ch+ca];
    float sgb = ng[ch+cb]*BN_INV, sbb = nbe[ch+cb];
    T[ca*130 + lane]      = fmaxf(rr[t][0]*(1.f/128.f)*sga + sba, 0.f);
    T[cb*130 + lane]      = fmaxf(rr[t][1]*(1.f/128.f)*sgb + sbb, 0.f);
    T[ca*130 + 64 + lane] = fmaxf(rr[t][2]*(1.f/128.f)*sga + sba, 0.f);
    T[cb*130 + 64 + lane] = fmaxf(rr[t][3]*(1.f/128.f)*sgb + sbb, 0.f);
  }
  __syncthreads();
  size_t sb0 = ((size_t)b*L_ + (size_t)h*128)*128 + ch;
  #pragma unroll
  for (int it = 0; it < 8; it++) {
    int idx = it*256 + tid;
    int c4 = (idx & 15)*4, w = idx >> 4;
    size_t off = sb0 + (size_t)w*128 + c4;
    float4 v;
    v.x = T[(c4+0)*130 + w];
    v.y = T[(c4+1)*130 + w];
    v.z = T[(c4+2)*130 + w];
    v.w = T[(c4+3)*130 + w];
    float4 x1 = *(const float4*)(add1 + off);
    float4 x2 = *(const float4*)(add2 + off);
    v.x += x1.x + x2.x; v.y += x1.y + x2.y;
    v.z += x1.z + x2.z; v.w += x1.w + x2.w;
    *(float4*)(out + off) = v;
  }
}

// ---------------------------------------------------------------- freq hidden (8ch) conv, half-plane (bf16 spectrum in)
__global__ __launch_bounds__(256) void k_freq1_h(const bf16_t* __restrict__ tre,
    const float* __restrict__ fw1, const float* __restrict__ fb1,
    const float* __restrict__ fg, const float* __restrict__ fbe,
    float* __restrict__ wg1) {
  __shared__ float w1s[1024];
  int tid = threadIdx.x;
  for (int i = tid; i < 1024; i += 256) w1s[i] = fw1[i];
  __syncthreads();
  size_t g = (size_t)blockIdx.x*256 + tid;   // (b,p) over B*L2_
  int p = (int)(g % L2_);
  int b = (int)(g / L2_);
  const bf16_t* tp = tre + (size_t)b*128*L2_ + p;
  float acc[8];
  #pragma unroll
  for (int o = 0; o < 8; o++) acc[o] = 0.f;
  for (int c = 0; c < 128; c++) {
    float v = ldf(tp[(size_t)c*L2_]);
    #pragma unroll
    for (int o = 0; o < 8; o++) acc[o] += w1s[o*128+c]*v;
  }
  size_t ob = (size_t)b*8*L2_ + p;
  #pragma unroll
  for (int o = 0; o < 8; o++) {
    float v = (acc[o] + fb1[o]) * (fg[o]*BN_INV) + fbe[o];
    wg1[ob + (size_t)o*L2_] = fmaxf(v, 0.f);
  }
}

// ---------------------------------------------------------------- planar->seq transpose
template<bool DUAL>
__global__ void k_p2s(const void* __restrict__ src, float* __restrict__ dst,
                      const float* __restrict__ add1, const float* __restrict__ add2,
                      const int* __restrict__ flagp) {
  __shared__ float tile[32][33];
  int fl = DUAL ? *flagp : 1;
  int b = blockIdx.z;
  int p0 = blockIdx.x*32, c0 = blockIdx.y*32;
  int tx = threadIdx.x, ty = threadIdx.y;
  size_t base_in = (size_t)b*NSP;
  #pragma unroll
  for (int k = 0; k < 4; k++) {
    size_t off = base_in + (size_t)(c0+ty+8*k)*L_ + p0 + tx;
    float v;
    if (DUAL && !fl) v = ldf(((const bf16_t*)src)[off]);
    else             v = ((const float*)src)[off];
    tile[ty+8*k][tx] = v;
  }
  __syncthreads();
  size_t base = (size_t)b*NSP;
  #pragma unroll
  for (int k = 0; k < 4; k++) {
    size_t idx = base + (size_t)(p0+ty+8*k)*C_ + c0 + tx;
    float v = tile[tx][ty+8*k];
    if (add1) v += add1[idx];
    if (add2) v += add2[idx];
    dst[idx] = v;
  }
}

// ---------------------------------------------------------------- depthwise 3x3 (NHWC fp32), residual add
template<int CC>  // out = in + dw + b
__global__ __launch_bounds__(256) void k_dw3(const float* __restrict__ in,
    const float* __restrict__ w, const float* __restrict__ bias,
    float* __restrict__ out) {
  __shared__ float wl[9*CC];
  int tid = threadIdx.x;
  for (int i = tid; i < 9*CC; i += 256) {
    int tap = i / CC, ch = i % CC;
    wl[i] = w[ch*9 + tap];
  }
  __syncthreads();
  size_t g = (size_t)blockIdx.x*256 + tid;
  int c = (int)(g & (CC-1));
  float wr[9];
  #pragma unroll
  for (int t = 0; t < 9; t++) wr[t] = wl[t*CC + c];
  size_t s = g / CC;
  int w0 = (int)(s & 31) * 4;
  int hp = (int)((s >> 5) & 127);
  int b  = (int)(s >> 12);
  const float* ip = in + (size_t)b*L_*CC + c;
  float bi = bias[c];
  float a0 = bi, a1 = bi, a2 = bi, a3 = bi;
  #pragma unroll
  for (int dh = -1; dh <= 1; dh++) {
    int h2 = hp + dh;
    if ((unsigned)h2 >= 128u) continue;
    const float* rp = ip + (size_t)h2*W_*CC;
    float px[6];
    #pragma unroll
    for (int x = 0; x < 6; x++) {
      int w2 = w0 - 1 + x;
      px[x] = ((unsigned)w2 < 128u) ? rp[(size_t)w2*CC] : 0.f;
    }
    #pragma unroll
    for (int dw = 0; dw < 3; dw++) {
      float f = wr[(dh+1)*3 + dw];
      a0 += f*px[dw];   a1 += f*px[dw+1];
      a2 += f*px[dw+2]; a3 += f*px[dw+3];
    }
  }
  size_t tb = (size_t)b*L_ + (size_t)hp*W_ + w0;
  out[(tb+0)*CC + c] = in[(tb+0)*CC + c] + a0;
  out[(tb+1)*CC + c] = in[(tb+1)*CC + c] + a1;
  out[(tb+2)*CC + c] = in[(tb+2)*CC + c] + a2;
  out[(tb+3)*CC + c] = in[(tb+3)*CC + c] + a3;
}

// ---------------------------------------------------------------- depthwise 3x3, 64ch, silu, bf16 in/out
__global__ __launch_bounds__(256) void k_dw3h(const bf16_t* __restrict__ in,
    const float* __restrict__ w, const float* __restrict__ bias,
    bf16_t* __restrict__ out) {
  __shared__ float wl[9*64];
  int tid = threadIdx.x;
  for (int i = tid; i < 9*64; i += 256) {
    int tap = i / 64, ch = i % 64;
    wl[i] = w[ch*9 + tap];
  }
  __syncthreads();
  size_t g = (size_t)blockIdx.x*256 + tid;
  int c = (int)(g & 63);
  float wr[9];
  #pragma unroll
  for (int t = 0; t < 9; t++) wr[t] = wl[t*64 + c];
  size_t s = g >> 6;
  int w0 = (int)(s & 31) * 4;
  int hp = (int)((s >> 5) & 127);
  int b  = (int)(s >> 12);
  const bf16_t* ip = in + (size_t)b*L_*64 + c;
  float bi = bias[c];
  float a0 = bi, a1 = bi, a2 = bi, a3 = bi;
  #pragma unroll
  for (int dh = -1; dh <= 1; dh++) {
    int h2 = hp + dh;
    if ((unsigned)h2 >= 128u) continue;
    const bf16_t* rp = ip + (size_t)h2*W_*64;
    float px[6];
    #pragma unroll
    for (int x = 0; x < 6; x++) {
      int w2 = w0 - 1 + x;
      px[x] = ((unsigned)w2 < 128u) ? ldf(rp[(size_t)w2*64]) : 0.f;
    }
    #pragma unroll
    for (int dw = 0; dw < 3; dw++) {
      float f = wr[(dh+1)*3 + dw];
      a0 += f*px[dw];   a1 += f*px[dw+1];
      a2 += f*px[dw+2]; a3 += f*px[dw+3];
    }
  }
  size_t tb = (size_t)b*L_ + (size_t)hp*W_ + w0;
  out[(tb+0)*64 + c] = f2b(a0 / (1.f + expf(-a0)));
  out[(tb+1)*64 + c] = f2b(a1 / (1.f + expf(-a1)));
  out[(tb+2)*64 + c] = f2b(a2 / (1.f + expf(-a2)));
  out[(tb+3)*64 + c] = f2b(a3 / (1.f + expf(-a3)));
}

// ---------------------------------------------------------------- grouped conv KxK (bf16 in/out), 4 pixels/thread
template<int K>
__global__ __launch_bounds__(256) void k_gconv(const bf16_t* __restrict__ in,
    const float* __restrict__ w, bf16_t* __restrict__ out) {
  __shared__ float wl[K*K*128];
  int tid = threadIdx.x;
  for (int i = tid; i < 128*K*K; i += 256) {
    int tap = i >> 7, ch = i & 127;
    wl[i] = w[ch*(K*K) + tap];
  }
  __syncthreads();
  size_t g = (size_t)blockIdx.x*256 + tid;
  int oc = (int)(g & 63);
  float wx[K*K], wy[K*K];
  #pragma unroll
  for (int t = 0; t < K*K; t++) {
    wx[t] = wl[t*128 + 2*oc];
    wy[t] = wl[t*128 + 2*oc + 1];
  }
  size_t s = g >> 6;
  int w0 = (int)(s & 31) * 4;
  int hp = (int)((s >> 5) & 127);
  int b  = (int)(s >> 12);
  const bf16_t* ip = in + (size_t)b*L_*128 + 2*oc;
  constexpr int P = K/2;
  float a0 = 0.f, a1 = 0.f, a2 = 0.f, a3 = 0.f;
  #pragma unroll
  for (int kh = 0; kh < K; kh++) {
    int h2 = hp + kh - P;
    if ((unsigned)h2 >= 128u) continue;
    const bf16_t* rp = ip + (size_t)h2*W_*128;
    float2 px[K+3];
    #pragma unroll
    for (int x = 0; x < K+3; x++) {
      int w2 = w0 - P + x;
      if ((unsigned)w2 < 128u) {
        unsigned uv = *(const unsigned*)(rp + (size_t)w2*128);
        px[x] = make_float2(ldf((bf16_t)(uv & 0xffffu)), ldf((bf16_t)(uv >> 16)));
      } else px[x] = make_float2(0.f, 0.f);
    }
    #pragma unroll
    for (int kw = 0; kw < K; kw++) {
      float fx = wx[kh*K + kw], fy = wy[kh*K + kw];
      a0 += fx*px[kw+0].x + fy*px[kw+0].y;
      a1 += fx*px[kw+1].x + fy*px[kw+1].y;
      a2 += fx*px[kw+2].x + fy*px[kw+2].y;
      a3 += fx*px[kw+3].x + fy*px[kw+3].y;
    }
  }
  size_t tb = (size_t)b*L_ + (size_t)hp*W_ + w0;
  out[(tb+0)*64 + oc] = f2b(a0);
  out[(tb+1)*64 + oc] = f2b(a1);
  out[(tb+2)*64 + oc] = f2b(a2);
  out[(tb+3)*64 + oc] = f2b(a3);
}

// ---------------------------------------------------------------- MFMA token GEMM (seq, bf16 W from global)
// IB16: 'in' is bf16 (direct fragment loads). mulp (if MUL) is bf16. OB16: bf16 output.
template<int CIN, int COUT, int EPI, bool MUL, bool IB16, bool OB16>   // EPI 0:none 1:bias 2:bias+silu 3:bias+elu+1
__global__ __launch_bounds__(256) void k_mfma_tok(
    const void* __restrict__ in, const bf16_t* __restrict__ mulp,
    const bf16_t* __restrict__ W16, const float* __restrict__ bias,
    void* __restrict__ out) {
  constexpr int NO = COUT/16;
  constexpr int KS = (CIN >= 128) ? 4 : (CIN/32);
  int tid = threadIdx.x;
  int lane = tid & 63, wv = tid >> 6;
  int m = lane & 15, q = lane >> 4;
  size_t t0 = (size_t)blockIdx.x*64 + (size_t)wv*16;
  f32x4 acc[NO];
  #pragma unroll
  for (int i = 0; i < NO; i++) acc[i] = (f32x4){0.f,0.f,0.f,0.f};
  for (int kc = 0; kc < CIN; kc += KS*32) {
    short8 afv[KS];
    if (IB16) {
      #pragma unroll
      for (int kk = 0; kk < KS; kk++)
        afv[kk] = *(const short8*)((const bf16_t*)in + (t0 + m)*CIN + kc + kk*32 + q*8);
    } else {
      float4 A[KS][2];
      #pragma unroll
      for (int kk = 0; kk < KS; kk++) {
        const float* ap = (const float*)in + (t0 + m)*CIN + kc + kk*32 + q*8;
        A[kk][0] = *(const float4*)ap;
        A[kk][1] = *(const float4*)(ap + 4);
      }
      if (MUL) {
        #pragma unroll
        for (int kk = 0; kk < KS; kk++) {
          const bf16_t* mp = mulp + (t0 + m)*CIN + kc + kk*32 + q*8;
          union { bf16_t u[8]; short8 v; } mv;
          mv.v = *(const short8*)mp;
          A[kk][0].x*=ldf(mv.u[0]); A[kk][0].y*=ldf(mv.u[1]);
          A[kk][0].z*=ldf(mv.u[2]); A[kk][0].w*=ldf(mv.u[3]);
          A[kk][1].x*=ldf(mv.u[4]); A[kk][1].y*=ldf(mv.u[5]);
          A[kk][1].z*=ldf(mv.u[6]); A[kk][1].w*=ldf(mv.u[7]);
        }
      }
      #pragma unroll
      for (int kk = 0; kk < KS; kk++) {
        union { short s[8]; short8 v; } af;
        af.s[0]=(short)f2b(A[kk][0].x); af.s[1]=(short)f2b(A[kk][0].y);
        af.s[2]=(short)f2b(A[kk][0].z); af.s[3]=(short)f2b(A[kk][0].w);
        af.s[4]=(short)f2b(A[kk][1].x); af.s[5]=(short)f2b(A[kk][1].y);
        af.s[6]=(short)f2b(A[kk][1].z); af.s[7]=(short)f2b(A[kk][1].w);
        afv[kk] = af.v;
      }
    }
    #pragma unroll
    for (int kk = 0; kk < KS; kk++) {
      #pragma unroll
      for (int o = 0; o < NO; o++) {
        short8 bf = *(const short8*)(W16 + (size_t)(o*16 + m)*CIN + kc + kk*32 + q*8);
        acc[o] = __builtin_amdgcn_mfma_f32_16x16x32_bf16(afv[kk], bf, acc[o], 0, 0, 0);
      }
    }
  }
  #pragma unroll
  for (int o = 0; o < NO; o++) {
    float bv = (EPI >= 1) ? bias[o*16 + m] : 0.f;
    #pragma unroll
    for (int r = 0; r < 4; r++) {
      int row = q*4 + r;
      float v = acc[o][r] + bv;
      if (EPI == 2) v = v / (1.f + expf(-v));
      if (EPI == 3) v = v > 0.f ? v + 1.f : expf(v);
      size_t idx = (t0 + row)*COUT + o*16 + m;
      if (OB16) ((bf16_t*)out)[idx] = f2b(v);
      else      ((float*)out)[idx] = v;
    }
  }
}

// ---------------------------------------------------------------- fused LN + 3 GEMMs (d3w1, d5w1, ap)
// combined 24-accumulator GEMM; bf16 outputs staged via LDS for coalesced 16B stores.
__global__ __launch_bounds__(256) void k_mfma_ln3(
    const float* __restrict__ in,
    const float* __restrict__ lng, const float* __restrict__ lnb,
    const bf16_t* __restrict__ Wd3, const float* __restrict__ bd3,
    const bf16_t* __restrict__ Wd5, const float* __restrict__ bd5,
    const bf16_t* __restrict__ Wap, const float* __restrict__ bap,
    bf16_t* __restrict__ outd3, bf16_t* __restrict__ outd5, bf16_t* __restrict__ outap) {
  __shared__ float gs[128], bs[128];
  __shared__ bf16_t T16[64*130];
  int tid = threadIdx.x;
  if (tid < 128) { gs[tid] = lng[tid]; bs[tid] = lnb[tid]; }
  __syncthreads();
  int lane = tid & 63, wv = tid >> 6;
  int m = lane & 15, q = lane >> 4;
  size_t t0 = (size_t)blockIdx.x*64 + (size_t)wv*16;
  size_t t0blk = (size_t)blockIdx.x*64;
  float4 A[4][2];
  #pragma unroll
  for (int kk = 0; kk < 4; kk++) {
    const float* ap = in + (t0 + m)*128 + kk*32 + q*8;
    A[kk][0] = *(const float4*)ap;
    A[kk][1] = *(const float4*)(ap + 4);
  }
  float s = 0.f, ss = 0.f;
  #pragma unroll
  for (int kk = 0; kk < 4; kk++)
    #pragma unroll
    for (int h = 0; h < 2; h++) {
      float4 v = A[kk][h];
      s  += v.x + v.y + v.z + v.w;
      ss += v.x*v.x + v.y*v.y + v.z*v.z + v.w*v.w;
    }
  s  += __shfl_xor(s, 16);  s  += __shfl_xor(s, 32);
  ss += __shfl_xor(ss, 16); ss += __shfl_xor(ss, 32);
  float mean = s*(1.f/128.f);
  float inv = rsqrtf(ss*(1.f/128.f) - mean*mean + 1e-5f);
  short8 af[4];
  #pragma unroll
  for (int kk = 0; kk < 4; kk++) {
    union { short sh[8]; short8 v; } u;
    #pragma unroll
    for (int h = 0; h < 2; h++) {
      const float* vp = (const float*)&A[kk][h];
      #pragma unroll
      for (int j = 0; j < 4; j++) {
        int c = kk*32 + q*8 + h*4 + j;
        float x = (vp[j] - mean)*inv*gs[c] + bs[c];
        u.sh[h*4+j] = (short)f2b(x);
      }
    }
    af[kk] = u.v;
  }
  f32x4 acc[24];
  #pragma unroll
  for (int i = 0; i < 24; i++) acc[i] = (f32x4){0.f,0.f,0.f,0.f};
  #pragma unroll
  for (int kk = 0; kk < 4; kk++) {
    #pragma unroll
    for (int o = 0; o < 8; o++) {
      size_t woff = (size_t)(o*16 + m)*128 + kk*32 + q*8;
      short8 b3 = *(const short8*)(Wd3 + woff);
      acc[o]    = __builtin_amdgcn_mfma_f32_16x16x32_bf16(af[kk], b3, acc[o],    0, 0, 0);
      short8 b5 = *(const short8*)(Wd5 + woff);
      acc[8+o]  = __builtin_amdgcn_mfma_f32_16x16x32_bf16(af[kk], b5, acc[8+o],  0, 0, 0);
      short8 ba = *(const short8*)(Wap + woff);
      acc[16+o] = __builtin_amdgcn_mfma_f32_16x16x32_bf16(af[kk], ba, acc[16+o], 0, 0, 0);
    }
  }
  #pragma unroll
  for (int mi = 0; mi < 3; mi++) {
    const float* bp = (mi == 0) ? bd3 : (mi == 1) ? bd5 : bap;
    bf16_t* op = (mi == 0) ? outd3 : (mi == 1) ? outd5 : outap;
    #pragma unroll
    for (int o = 0; o < 8; o++) {
      float bv = bp[o*16 + m];
      #pragma unroll
      for (int r = 0; r < 4; r++) {
        float v = acc[mi*8 + o][r] + bv;
        if (mi == 2) v = v / (1.f + expf(-v));
        T16[(wv*16 + q*4 + r)*130 + o*16 + m] = f2b(v);
      }
    }
    __syncthreads();
    for (int i = tid; i < 1024; i += 256) {
      int tok = i >> 4, c0 = (i & 15) * 8;
      union { bf16_t u[8]; short8 v; } pk;
      #pragma unroll
      for (int j = 0; j < 8; j++) pk.u[j] = T16[tok*130 + c0 + j];
      *(short8*)(op + (t0blk + tok)*128 + c0) = pk.v;
    }
    __syncthreads();
  }
}

// ---------------------------------------------------------------- MFMA c1: seq in -> relu(bn(conv1x1)) -> bf16 seq out
__global__ __launch_bounds__(256) void k_mfma_c1(
    const float* __restrict__ in, const bf16_t* __restrict__ W16,
    const float* __restrict__ bias, const float* __restrict__ gam,
    const float* __restrict__ bet, bf16_t* __restrict__ out) {
  __shared__ bf16_t T16[64*130];
  constexpr int NO = 8;
  int tid = threadIdx.x;
  int lane = tid & 63, wv = tid >> 6;
  int m = lane & 15, q = lane >> 4;
  size_t t0 = (size_t)blockIdx.x*64 + (size_t)wv*16;
  size_t t0blk = (size_t)blockIdx.x*64;
  f32x4 acc[NO];
  #pragma unroll
  for (int i = 0; i < NO; i++) acc[i] = (f32x4){0.f,0.f,0.f,0.f};
  {
    float4 A[4][2];
    #pragma unroll
    for (int kk = 0; kk < 4; kk++) {
      const float* ap = in + (t0 + m)*128 + kk*32 + q*8;
      A[kk][0] = *(const float4*)ap;
      A[kk][1] = *(const float4*)(ap + 4);
    }
    #pragma unroll
    for (int kk = 0; kk < 4; kk++) {
      union { short s[8]; short8 v; } af;
      af.s[0]=(short)f2b(A[kk][0].x); af.s[1]=(short)f2b(A[kk][0].y);
      af.s[2]=(short)f2b(A[kk][0].z); af.s[3]=(short)f2b(A[kk][0].w);
      af.s[4]=(short)f2b(A[kk][1].x); af.s[5]=(short)f2b(A[kk][1].y);
      af.s[6]=(short)f2b(A[kk][1].z); af.s[7]=(short)f2b(A[kk][1].w);
      #pragma unroll
      for (int o = 0; o < NO; o++) {
        short8 bf = *(const short8*)(W16 + (size_t)(o*16 + m)*128 + kk*32 + q*8);
        acc[o] = __builtin_amdgcn_mfma_f32_16x16x32_bf16(af.v, bf, acc[o], 0, 0, 0);
      }
    }
  }
  #pragma unroll
  for (int o = 0; o < NO; o++) {
    int oc = o*16 + m;
    float bi = bias[oc], gm = gam[oc]*BN_INV, be = bet[oc];
    #pragma unroll
    for (int r = 0; r < 4; r++) {
      float v = acc[o][r] + bi;
      T16[(wv*16 + q*4 + r)*130 + oc] = f2b(fmaxf(v*gm + be, 0.f));
    }
  }
  __syncthreads();
  for (int i = tid; i < 1024; i += 256) {
    int tok = i >> 4, c0 = (i & 15) * 8;
    union { bf16_t u[8]; short8 v; } pk;
    #pragma unroll
    for (int j = 0; j < 8; j++) pk.u[j] = T16[tok*130 + c0 + j];
    *(short8*)(out + (t0blk + tok)*128 + c0) = pk.v;
  }
}

// ---------------------------------------------------------------- MFMA red (po folded in):
// out = relu(bn(R0@x0 + (R1@Wpo)@xt4)) + x0; x0 seq is bf16; planar out via LDS transpose.
__global__ __launch_bounds__(256) void k_mfma_red(
    const bf16_t* __restrict__ x0s, const float* __restrict__ xt4,
    const bf16_t* __restrict__ W16, const float* __restrict__ bias,
    const float* __restrict__ gam, const float* __restrict__ bet,
    void* __restrict__ out, const int* __restrict__ flagp) {
  __shared__ float T[128*65];
  constexpr int NO = 8;
  int fl = *flagp;
  int tid = threadIdx.x;
  int lane = tid & 63, wv = tid >> 6;
  int m = lane & 15, q = lane >> 4;
  size_t t0 = (size_t)blockIdx.x*64;
  size_t tw = t0 + (size_t)wv*16;
  f32x4 acc[NO];
  #pragma unroll
  for (int i = 0; i < NO; i++) acc[i] = (f32x4){0.f,0.f,0.f,0.f};
  // half 0: x0 (bf16, direct fragments)
  #pragma unroll
  for (int kk = 0; kk < 4; kk++) {
    short8 afv = *(const short8*)(x0s + (tw + m)*128 + kk*32 + q*8);
    #pragma unroll
    for (int o = 0; o < NO; o++) {
      short8 bf = *(const short8*)(W16 + (size_t)(o*16 + m)*256 + kk*32 + q*8);
      acc[o] = __builtin_amdgcn_mfma_f32_16x16x32_bf16(afv, bf, acc[o], 0, 0, 0);
    }
  }
  // half 1: xt4 (fp32 -> bf16)
  {
    float4 A[4][2];
    #pragma unroll
    for (int kk = 0; kk < 4; kk++) {
      const float* ap = xt4 + (tw + m)*128 + kk*32 + q*8;
      A[kk][0] = *(const float4*)ap;
      A[kk][1] = *(const float4*)(ap + 4);
    }
    #pragma unroll
    for (int kk = 0; kk < 4; kk++) {
      union { short s[8]; short8 v; } af;
      af.s[0]=(short)f2b(A[kk][0].x); af.s[1]=(short)f2b(A[kk][0].y);
      af.s[2]=(short)f2b(A[kk][0].z); af.s[3]=(short)f2b(A[kk][0].w);
      af.s[4]=(short)f2b(A[kk][1].x); af.s[5]=(short)f2b(A[kk][1].y);
      af.s[6]=(short)f2b(A[kk][1].z); af.s[7]=(short)f2b(A[kk][1].w);
      #pragma unroll
      for (int o = 0; o < NO; o++) {
        short8 bf = *(const short8*)(W16 + (size_t)(o*16 + m)*256 + 128 + kk*32 + q*8);
        acc[o] = __builtin_amdgcn_mfma_f32_16x16x32_bf16(af.v, bf, acc[o], 0, 0, 0);
      }
    }
  }
  #pragma unroll
  for (int ot = 0; ot < NO; ot++) {
    int o = ot*16 + m;
    float bi = bias[o], gm = gam[o]*BN_INV, be = bet[o];
    #pragma unroll
    for (int r = 0; r < 4; r++) {
      int row = q*4 + r;
      float v = acc[ot][r] + bi;
      v = fmaxf(v*gm + be, 0.f);
      v += ldf(x0s[(tw + row)*128 + o]);
      T[o*65 + wv*16 + row] = v;
    }
  }
  __syncthreads();
  int b = (int)(t0 >> 14);
  int p0 = (int)(t0 & (L_-1));
  if (!fl) {
    bf16_t* op = (bf16_t*)out;
    for (int i = tid; i < 8192; i += 256) {
      int o = i >> 6, tk = i & 63;
      op[((size_t)b*128 + o)*L_ + p0 + tk] = f2b(T[o*65 + tk]);
    }
  } else {
    float* op = (float*)out;
    for (int i = tid; i < 8192; i += 256) {
      int o = i >> 6, tk = i & 63;
      op[((size_t)b*128 + o)*L_ + p0 + tk] = T[o*65 + tk];
    }
  }
}

// ---------------------------------------------------------------- LN+FFN
__global__ __launch_bounds__(256) void k_ln_ffn(const float* __restrict__ in,
    const float* __restrict__ g, const float* __restrict__ be,
    const float* __restrict__ w1, const float* __restrict__ b1,
    const float* __restrict__ w2, const float* __restrict__ b2,
    float* __restrict__ out) {
  int tid = threadIdx.x, lane = tid & 63;
  size_t t = (size_t)blockIdx.x*4 + (tid >> 6);
  const float* row = in + t*128;
  float2 v = *(const float2*)(row + lane*2);
  float s = v.x + v.y, ss = v.x*v.x + v.y*v.y;
  #pragma unroll
  for (int m = 1; m < 64; m <<= 1) { s += __shfl_xor(s, m); ss += __shfl_xor(ss, m); }
  float mean = s*(1.f/128.f);
  float inv = rsqrtf(ss*(1.f/128.f) - mean*mean + 1e-5f);
  float hx = (v.x-mean)*inv*g[lane*2]   + be[lane*2];
  float hy = (v.y-mean)*inv*g[lane*2+1] + be[lane*2+1];
  float hp0 = hx*w1[0*128+lane*2] + hy*w1[0*128+lane*2+1];
  float hp1 = hx*w1[1*128+lane*2] + hy*w1[1*128+lane*2+1];
  float hp2 = hx*w1[2*128+lane*2] + hy*w1[2*128+lane*2+1];
  float hp3 = hx*w1[3*128+lane*2] + hy*w1[3*128+lane*2+1];
  #pragma unroll
  for (int m = 1; m < 64; m <<= 1) {
    hp0 += __shfl_xor(hp0, m); hp1 += __shfl_xor(hp1, m);
    hp2 += __shfl_xor(hp2, m); hp3 += __shfl_xor(hp3, m);
  }
  float hv0, hv1, hv2, hv3;
  { float a = hp0 + b1[0]; hv0 = 0.5f*a*(1.f+erff(a*0.7071067811865476f)); }
  { float a = hp1 + b1[1]; hv1 = 0.5f*a*(1.f+erff(a*0.7071067811865476f)); }
  { float a = hp2 + b1[2]; hv2 = 0.5f*a*(1.f+erff(a*0.7071067811865476f)); }
  { float a = hp3 + b1[3]; hv3 = 0.5f*a*(1.f+erff(a*0.7071067811865476f)); }
  int cx = lane*2, cy = lane*2+1;
  float2 o;
  o.x = hv0*w2[cx*4+0] + hv1*w2[cx*4+1] + hv2*w2[cx*4+2] + hv3*w2[cx*4+3] + b2[cx];
  o.y = hv0*w2[cy*4+0] + hv1*w2[cy*4+1] + hv2*w2[cy*4+2] + hv3*w2[cy*4+3] + b2[cy];
  *(float2*)(out + t*128 + lane*2) = o;
}

// ---------------------------------------------------------------- linear attention (qk, v, x all bf16)
__global__ __launch_bounds__(256) void k_kv(
    const bf16_t* __restrict__ qk, const bf16_t* __restrict__ v,
    float* __restrict__ akv_g, float* __restrict__ aks_g) {
  __shared__ float kvred[512];
  __shared__ float ksred[64];
  int tid = threadIdx.x;
  for (int i = tid; i < 512; i += 256) kvred[i] = 0.f;
  if (tid < 64) ksred[tid] = 0.f;
  __syncthreads();
  int lane = tid & 63, wv = tid >> 6;
  size_t t0 = (size_t)blockIdx.x * 64;
  int b = (int)(t0 >> 14);
  int pr = lane >> 1;
  float theta = exp2f(-(float)(pr & 15) * THETA_SC);
  bool use_i = pr < 16;
  int hbase = lane & 56;
  float akv[8];
  #pragma unroll
  for (int d = 0; d < 8; d++) akv[d] = 0.f;
  float aks = 0.f;
  for (int it = 0; it < 16; it++) {
    size_t t = t0 + (size_t)wv*16 + it;
    float k = ldf(qk[t*128 + 64 + lane]);
    float xv = ldf(v[t*64 + lane]);
    int l = (int)(t & (L_-1));
    float pos = use_i ? (float)(l >> 7) : (float)(l & 127);
    float sn, cs; sincosf(pos*theta, &sn, &cs);
    float kp = __shfl_xor(k, 1);
    float kr = (lane & 1) ? (sn*kp + cs*k) : (cs*k - sn*kp);
    #pragma unroll
    for (int d = 0; d < 8; d++) {
      float krd = __shfl(kr, hbase + d);
      akv[d] += krd * xv;
    }
    aks += k;
  }
  int h8 = lane >> 3, e = lane & 7;
  #pragma unroll
  for (int d = 0; d < 8; d++)
    atomicAdd(&kvred[h8*64 + d*8 + e], akv[d]);
  atomicAdd(&ksred[lane], aks);
  __syncthreads();
  for (int i = tid; i < 512; i += 256) atomicAdd(&akv_g[b*512 + i], kvred[i]);
  if (tid < 64) atomicAdd(&aks_g[b*64 + tid], ksred[tid]);
}

__global__ __launch_bounds__(256) void k_attn2(
    const bf16_t* __restrict__ qk, const bf16_t* __restrict__ x,
    const float* __restrict__ akv_g, const float* __restrict__ aks_g,
    const float* __restrict__ lw, const float* __restrict__ lb,
    float* __restrict__ out, int coff) {
  __shared__ float kv[512];
  __shared__ float km[64];
  __shared__ float lwl[576];
  int tid = threadIdx.x;
  size_t t0 = (size_t)blockIdx.x * 32;
  int b = (int)(t0 >> 14);
  const float invn = 1.f/16384.f;
  for (int i = tid; i < 512; i += 256) kv[i] = akv_g[b*512 + i]*invn;
  if (tid < 64) km[tid] = aks_g[b*64 + tid]*invn;
  for (int i = tid; i < 576; i += 256) lwl[i] = lw[i];
  __syncthreads();
  int lane = tid & 63, wv = tid >> 6;
  int pr = lane >> 1;
  float theta = exp2f(-(float)(pr & 15) * THETA_SC);
  bool use_i = pr < 16;
  int hbase = lane & 56, e = lane & 7;
  float lbv = lb[lane];
  const bf16_t* xb = x + ((size_t)b << 14) * 64;
  for (int it = 0; it < 8; it++) {
    size_t t = t0 + (size_t)wv*8 + it;
    int l = (int)(t & (L_-1));
    int ipos = l >> 7, jpos = l & 127;
    float q = ldf(qk[t*128 + lane]);
    float p = q * km[lane];
    p += __shfl_xor(p, 1); p += __shfl_xor(p, 2); p += __shfl_xor(p, 4);
    float z = 1.f/(p + 1e-6f);
    float pos = use_i ? (float)ipos : (float)jpos;
    float sn, cs; sincosf(pos*theta, &sn, &cs);
    float qp = __shfl_xor(q, 1);
    float qr = (lane & 1) ? (sn*qp + cs*q) : (cs*q - sn*qp);
    float acc = 0.f;
    #pragma unroll
    for (int d = 0; d < 8; d++) {
      float qrd = __shfl(qr, hbase + d);
      acc += qrd * kv[hbase*8 + d*8 + e];
    }
    acc *= z;
    float lp = lbv;
    #pragma unroll
    for (int dh = -1; dh <= 1; dh++) {
      int h2 = ipos + dh; if ((unsigned)h2 >= 128u) continue;
      #pragma unroll
      for (int dw = -1; dw <= 1; dw++) {
        int w2 = jpos + dw; if ((unsigned)w2 >= 128u) continue;
        lp += lwl[lane*9 + (dh+1)*3 + (dw+1)] * ldf(xb[((size_t)(h2 << 7) + w2)*64 + lane]);
      }
    }
    out[t*128 + coff + lane] = acc + lp;
  }
}

// ---------------------------------------------------------------- launcher
extern "C" void kernel_launch(void* const* d_in, const int* in_sizes, int n_in,
                              void* d_out, int out_size, void* d_ws, size_t ws_size,
                              hipStream_t stream) {
  (void)in_sizes; (void)n_in; (void)out_size;

  float* base;
  if (ws_size >= WSF * sizeof(float)) {
    base = (float*)d_ws;
  } else {
    void* p = nullptr;
    hipGetSymbolAddress(&p, HIP_SYMBOL(g_ws));
    base = (float*)p;
  }
  float* P0 = base;          // x0 (seq, bf16, persists)
  float* PA = base + 1*NS;   // xseq / ACT(bf16)
  float* PB = base + 2*NS;   // xt shortcut / xt2 / fmt2 re(bf16)
  float* PC = base + 3*NS;   // fmt1 re(bf16) / xt3 / xt4
  float* PD = base + 4*NS;   // d3-out(bf16) / QK(bf16) / fmt im(bf16)
  float* PF = base + 5*NS;   // d5-out(bf16) / CAT / xss / FFN
  float* H0 = base + 6*NS;   // bf16 branch bufs
  float* H1 = H0 + NH;
  float* H2 = H1 + NH;
  float* WG = H2 + NH;                  // B*8*L2_
  float* ACC = WG + WGSLOT;             // 2304
  float* CW  = ACC + ACCSZ;             // fp32 weights
  bf16_t* CW16 = (bf16_t*)(CW + CWSZ);  // bf16 weight mirror
  int*   FLG = (int*)(CW + CWSZ + CW16SZF);

  static const int wsz[47] = {
    16384,128,128,128,1152,128,1024,8,8,8,1024,128,128,128,128,128,
    16384,128,1152,16384,128,3200,16384,128,4096,64,576,64,8192,128,
    576,64,16384,128,1152,128,128,128,512,4,512,128,16384,32768,128,128,128};
  int woff[47]; { int a = 0; for (int i = 0; i < 47; i++){ woff[i] = a; a += wsz[i]; } }
  const float* Wf[47]; for (int i = 0; i < 47; i++) Wf[i] = CW + woff[i];
  auto W16 = [&](int i){ return (const bf16_t*)(CW16 + woff[i] + (woff[i] >= W16SHIFT ? 4 : 0)); };
  const float *c1_b=Wf[1], *c1_g=Wf[2], *c1_be=Wf[3], *cpe1_w=Wf[4],
    *cpe1_b=Wf[5], *fw1=Wf[6], *fb1=Wf[7], *f_g=Wf[8], *f_be=Wf[9], *fw2=Wf[10],
    *fb2=Wf[11], *nbn_g=Wf[12], *nbn_be=Wf[13], *ln1_g=Wf[14], *ln1_b=Wf[15],
    *d3b1=Wf[17], *d3w2=Wf[18], *d5b1=Wf[20],
    *d5w2=Wf[21], *ap_b=Wf[23], *ip2_b=Wf[25],
    *dwc2_w=Wf[26], *dwc2_b=Wf[27], *qk_b=Wf[29], *lepe_w=Wf[30],
    *lepe_b=Wf[31], *op_b=Wf[33], *cpe2_w=Wf[34], *cpe2_b=Wf[35],
    *ln2_g=Wf[36], *ln2_b=Wf[37], *ffn_w1=Wf[38], *ffn_b1=Wf[39], *ffn_w2=Wf[40],
    *ffn_b2=Wf[41], *red_b=Wf[44], *red_g=Wf[45], *red_be=Wf[46];
  const bf16_t *c1_w16=W16(0), *d3w1_16=W16(16), *d5w1_16=W16(19), *ap_w16=W16(22),
    *ip2_w16=W16(24), *qk_w16=W16(28), *op_w16=W16(32), *red_w16=W16(43);

  const void* x = d_in[0];

  // 0. dtype probe + weight conversion (fp32 + bf16 mirror + fused po->red weight)
  k_probe<<<1, 256, 0, stream>>>((const bf16_t*)x, FLG);
  P47 ps; for (int i = 0; i < 47; i++) ps.p[i] = d_in[i+1];
  k_cvt<<<(TOTW+255)/256, 256, 0, stream>>>(ps, FLG, CW);
  k_cvt16<<<(TOTW+255)/256, 256, 0, stream>>>(CW, CW16);
  k_fuse_red<<<64, 256, 0, stream>>>(CW + WOFF_PO, CW + WOFF_RED,
                                     (bf16_t*)(CW16 + WOFF_RED + 4));

  dim3 tgrid(512, 4, 4), tblk(32, 8);

  // fully fused fmt, Hermitian half-spectrum pipeline (bf16 spectrum storage)
  auto fmt_fused = [&](const float* seq_in, bf16_t* re, bf16_t* im,
                       const float* add1, const float* add2, float* outp) {
    k_fft_row_fwd_half<<<1024, 256, 0, stream>>>(seq_in, re, im);
    k_fft_col_fwd_h<<<1024, 256, 0, stream>>>(re, im);
    k_freq1_h<<<132, 256, 0, stream>>>(re, fw1, fb1, f_g, f_be, WG);
    k_fft_col_inv_scaled_h<<<1024, 256, 0, stream>>>(re, im, WG, fw2, fb2);
    k_fft_row_inv_abs_seq_h<<<1024, 256, 0, stream>>>(re, im, nbn_g, nbn_be, add1, add2, outp);
  };

  auto attn = [&](const bf16_t* brin, float* qkbuf, int coff) {
    k_zero<<<9, 256, 0, stream>>>(ACC, 2304);
    k_mfma_tok<64,128,3,false,true,true><<<1024, 256, 0, stream>>>(brin, nullptr, qk_w16, qk_b, qkbuf);
    k_kv<<<1024, 256, 0, stream>>>((const bf16_t*)qkbuf, brin, ACC, ACC + B_*512);
    k_attn2<<<2048, 256, 0, stream>>>((const bf16_t*)qkbuf, brin, ACC, ACC + B_*512, lepe_w, lepe_b, PF, coff);
  };

  // x -> seq                                               -> PA
  k_p2s<true><<<tgrid, tblk, 0, stream>>>(x, PA, nullptr, nullptr, FLG);
  // x_0 = relu(bn(conv1x1(x)))                             -> P0 (SEQ, bf16)
  k_mfma_c1<<<1024, 256, 0, stream>>>(PA, c1_w16, c1_b, c1_g, c1_be, (bf16_t*)P0);
  // xt = x + dw3(x,cpe1)+b                                 -> PB (shortcut)
  k_dw3<128><<<8192, 256, 0, stream>>>(PA, cpe1_w, cpe1_b, PB);
  // fused LN + {d3w1, d5w1, ap} GEMMs: xt -> PD(bf16), PF(bf16), PA(ACT bf16)
  k_mfma_ln3<<<1024, 256, 0, stream>>>(PB, ln1_g, ln1_b,
      d3w1_16, d3b1, d5w1_16, d5b1, ap_w16, ap_b,
      (bf16_t*)PD, (bf16_t*)PF, (bf16_t*)PA);
  // grouped convs consume PD/PF before attn reuses PF      -> H0/H1 (bf16)
  k_gconv<3><<<4096, 256, 0, stream>>>((const bf16_t*)PD, d3w2, (bf16_t*)H0);
  k_gconv<5><<<4096, 256, 0, stream>>>((const bf16_t*)PF, d5w2, (bf16_t*)H1);
  // branch3 -> attention -> CAT[:, :, 0:64] in PF
  k_mfma_tok<64,64,1,false,true,true><<<1024, 256, 0, stream>>>((const bf16_t*)H0, nullptr, ip2_w16, ip2_b, (bf16_t*)H2);
  k_dw3h<<<4096, 256, 0, stream>>>((const bf16_t*)H2, dwc2_w, dwc2_b, (bf16_t*)H0);
  attn((const bf16_t*)H0, PD, 0);
  // branch5 -> attention -> CAT[:, :, 64:128]
  k_mfma_tok<64,64,1,false,true,true><<<1024, 256, 0, stream>>>((const bf16_t*)H1, nullptr, ip2_w16, ip2_b, (bf16_t*)H2);
  k_dw3h<<<4096, 256, 0, stream>>>((const bf16_t*)H2, dwc2_w, dwc2_b, (bf16_t*)H1);
  attn((const bf16_t*)H1, PD, 64);
  // xss = conv1x1(CAT * ACT, op_w)+op_b                    -> PF (in-place)
  k_mfma_tok<128,128,1,true,false,false><<<1024, 256, 0, stream>>>(PF, (const bf16_t*)PA, op_w16, op_b, PF);
  // fmt1 (delayed) + xt2 = shortcut + xss + fmt1           -> PB
  fmt_fused(PB, (bf16_t*)PC, (bf16_t*)PD, PB, PF, PB);
  // xt3 = xt2 + dw3(xt2,cpe2)+b                            -> PC
  k_dw3<128><<<8192, 256, 0, stream>>>(PB, cpe2_w, cpe2_b, PC);
  // ffn(ln2(xt3))                                          -> PF
  k_ln_ffn<<<16384, 256, 0, stream>>>(PC, ln2_g, ln2_b, ffn_w1, ffn_b1, ffn_w2, ffn_b2, PF);
  // fmt2 + xt4 = xt3 + ffn + fmt2                          -> PC
  fmt_fused(PC, (bf16_t*)PB, (bf16_t*)PD, PC, PF, PC);
  // out = relu(bn(conv1x1([x0; po(xt4)], red_fused))) + x0 -> d_out (po folded into red)
  k_mfma_red<<<1024, 256, 0, stream>>>((const bf16_t*)P0, PC, red_w16, red_b, red_g, red_be, d_out, FLG);
}

// Round 12
// 899.824 us; speedup vs baseline: 1.0159x; 1.0159x over previous
//
#include <hip/hip_runtime.h>
#include <math.h>

typedef unsigned short bf16_t;
typedef __attribute__((ext_vector_type(8))) short short8;
typedef __attribute__((ext_vector_type(4))) float f32x4;

#define B_ 4
#define C_ 128
#define H_ 128
#define W_ 128
#define L_ (H_*W_)               // 16384
#define NS  ((size_t)B_*L_*C_)   // 8388608 elems
#define NH  ((size_t)B_*L_*64)
#define NSP ((size_t)L_*C_)
#define PI_F 3.14159265358979323846f
#define BN_INV 0.9999950000374997f   // (1+1e-5)^-0.5
#define THETA_SC 0.8304820237218406f // log2(10000)/16
#define TOTW 157148
#define W16SHIFT 107548              // offsets >= this get +4 in bf16 mirror (8-align po_w/red_w)
#define WOFF_PO 107612
#define WOFF_RED 123996

// half-spectrum geometry: cols v=0..64 stored, padded to 66 (col 65 = 0)
#define W2_ 66
#define L2_ (128*W2_)            // 8448 per channel plane

__device__ __forceinline__ float ldf(bf16_t v){ return __uint_as_float(((unsigned)v)<<16); }
__device__ __forceinline__ bf16_t f2b(float f){
  unsigned u = __float_as_uint(f);
  u += 0x7fffu + ((u>>16)&1u);     // RNE
  return (bf16_t)(u>>16);
}

// workspace layout
#define WGSLOT ((size_t)B_*8*L_)
#define ACCSZ 2304
#define CWSZ 157184                  // fp32 weights
#define CW16SZF 78592                // bf16 mirror in floats
#define WSF (6*NS + 3*NH + WGSLOT + ACCSZ + CWSZ + CW16SZF + 16)
__device__ float g_ws[WSF];

// ---------------------------------------------------------------- dtype probe + weight convert
__global__ void k_probe(const bf16_t* __restrict__ xb, int* __restrict__ flag){
  __shared__ int vote;
  if (threadIdx.x == 0) vote = 0;
  __syncthreads();
  int bad = 0;
  for (int i = threadIdx.x; i < 2048; i += 256) {
    float v = ldf(xb[2*i]);
    if (!(fabsf(v) < 1e6f)) bad = 1;
  }
  if (bad) atomicOr(&vote, 1);
  __syncthreads();
  if (threadIdx.x == 0) *flag = vote;  // 1 = fp32 storage, 0 = bf16 storage
}

struct P47 { const void* p[47]; };
__device__ __constant__ int c_wsz[47] = {
  16384,128,128,128,1152,128,1024,8,8,8,1024,128,128,128,128,128,
  16384,128,1152,16384,128,3200,16384,128,4096,64,576,64,8192,128,
  576,64,16384,128,1152,128,128,128,512,4,512,128,16384,32768,128,128,128};

__global__ __launch_bounds__(256) void k_cvt(P47 ps, const int* __restrict__ flagp,
                                             float* __restrict__ dst){
  int g = blockIdx.x*256 + threadIdx.x;
  if (g >= TOTW) return;
  int fl = *flagp;
  int idx = 0, off = g;
  while (off >= c_wsz[idx]) { off -= c_wsz[idx]; idx++; }
  const void* s = ps.p[idx];
  dst[g] = fl ? ((const float*)s)[off] : ldf(((const bf16_t*)s)[off]);
}

__global__ __launch_bounds__(256) void k_cvt16(const float* __restrict__ src, bf16_t* __restrict__ dst){
  int g = blockIdx.x*256 + threadIdx.x;
  if (g >= TOTW) return;
  dst[g + (g >= W16SHIFT ? 4 : 0)] = f2b(src[g]);
}

// fold po into red: red_w[:,128+in] <- sum_j red_w[:,128+j] * po_w[j][in]
__global__ __launch_bounds__(256) void k_fuse_red(const float* __restrict__ po,
    const float* __restrict__ rw, bf16_t* __restrict__ dst16){
  int g = blockIdx.x*256 + threadIdx.x;   // o*128 + in, 16384 total
  int o = g >> 7, in = g & 127;
  float acc = 0.f;
  for (int j = 0; j < 128; j++) acc += rw[o*256 + 128 + j] * po[j*128 + in];
  dst16[o*256 + 128 + in] = f2b(acc);
}

__global__ void k_zero(float* p, int n){
  int i = blockIdx.x*256 + threadIdx.x;
  if (i < n) p[i] = 0.f;
}

// ---------------------------------------------------------------- FFT core (hoisted twiddles)
__device__ __forceinline__ void tw_fwd(int lane, float* tc, float* ts) {
  sincosf(-PI_F * (float)lane * (1.f/64.f), &ts[0], &tc[0]);
  int i = 1;
  #pragma unroll
  for (int m = 32; m >= 1; m >>= 1, i++) {
    int k = lane & (m-1);
    sincosf(-PI_F * (float)k / (float)m, &ts[i], &tc[i]);
  }
}
__device__ __forceinline__ void tw_inv(int lane, float* tc, float* ts) {
  int i = 0;
  #pragma unroll
  for (int m = 1; m <= 32; m <<= 1, i++) {
    int k = lane & (m-1);
    sincosf(PI_F * (float)k / (float)m, &ts[i], &tc[i]);
  }
  sincosf(PI_F * (float)lane * (1.f/64.f), &ts[6], &tc[6]);
}

// DIF network: output lo[p] = X(2*br6(p)), hi[p] = X(2*br6(p)+1)
__device__ __forceinline__ void fft128_fwd(float& lor, float& loi, float& hir, float& hii,
                                           int lane, const float* tc, const float* ts) {
  {
    float s = ts[0], c = tc[0];
    float ar = lor, ai = loi;
    float dr = ar - hir, di = ai - hii;
    lor = ar + hir; loi = ai + hii;
    hir = dr*c - di*s; hii = dr*s + di*c;
  }
  int i = 1;
  #pragma unroll
  for (int m = 32; m >= 1; m >>= 1, i++) {
    float s = ts[i], c = tc[i];
    bool up = (lane & m) != 0;
    {
      float orr = __shfl_xor(lor, m), oii = __shfl_xor(loi, m);
      float sr = lor + orr, si = loi + oii;
      float dr = orr - lor, di = oii - loi;
      float tr = dr*c - di*s, ti = dr*s + di*c;
      lor = up ? tr : sr; loi = up ? ti : si;
    }
    {
      float orr = __shfl_xor(hir, m), oii = __shfl_xor(hii, m);
      float sr = hir + orr, si = hii + oii;
      float dr = orr - hir, di = oii - hii;
      float tr = dr*c - di*s, ti = dr*s + di*c;
      hir = up ? tr : sr; hii = up ? ti : si;
    }
  }
}

// DIT network: input lo[p] = W(2*br6(p)), hi[p] = W(2*br6(p)+1); output natural n
__device__ __forceinline__ void fft128_inv(float& lor, float& loi, float& hir, float& hii,
                                           int lane, const float* tc, const float* ts) {
  int i = 0;
  #pragma unroll
  for (int m = 1; m <= 32; m <<= 1, i++) {
    float s = ts[i], c = tc[i];
    bool up = (lane & m) != 0;
    {
      float orr = __shfl_xor(lor, m), oii = __shfl_xor(loi, m);
      float qr = orr*c - oii*s, qi = orr*s + oii*c;
      float lo_r = lor + qr, lo_i = loi + qi;
      float mr = lor*c - loi*s, mi = lor*s + loi*c;
      float up_r = orr - mr, up_i = oii - mi;
      lor = up ? up_r : lo_r; loi = up ? up_i : lo_i;
    }
    {
      float orr = __shfl_xor(hir, m), oii = __shfl_xor(hii, m);
      float qr = orr*c - oii*s, qi = orr*s + oii*c;
      float lo_r = hir + qr, lo_i = hii + qi;
      float mr = hir*c - hii*s, mi = hir*s + hii*c;
      float up_r = orr - mr, up_i = oii - mi;
      hir = up ? up_r : lo_r; hii = up ? up_i : lo_i;
    }
  }
  {
    float s = ts[6], c = tc[6];
    float qr = hir*c - hii*s, qi = hir*s + hii*c;
    float pr = lor, pi = loi;
    lor = pr + qr; loi = pi + qi;
    hir = pr - qr; hii = pi - qi;
  }
}

// fused seq-read + transpose + forward row FFT, 2 real channels packed per complex FFT.
// Spectrum stored in bf16 (packed dword stores for the (even,odd) column pair).
__global__ __launch_bounds__(256) void k_fft_row_fwd_half(
    const float* __restrict__ in, bf16_t* __restrict__ re, bf16_t* __restrict__ im) {
  __shared__ float T[64*130];
  int tid = threadIdx.x;
  int bid = blockIdx.x;
  int ch = (bid & 1) * 64;
  int h  = (bid >> 1) & 127;
  int b  = bid >> 8;
  const float* ip = in + ((size_t)b*L_ + (size_t)h*128)*128 + ch;
  #pragma unroll
  for (int it = 0; it < 8; it++) {
    int idx = it*256 + tid;            // 2048 float4 loads
    int c4 = (idx & 15)*4, w = idx >> 4;
    float4 v = *(const float4*)(ip + (size_t)w*128 + c4);
    T[(c4+0)*130 + w] = v.x;
    T[(c4+1)*130 + w] = v.y;
    T[(c4+2)*130 + w] = v.z;
    T[(c4+3)*130 + w] = v.w;
  }
  __syncthreads();
  int lane = tid & 63, wv = tid >> 6;
  int rb = (int)(__brev((unsigned)lane) >> 26);   // br6
  int pe = (64 - lane) & 63;
  int po = 63 - lane;
  float tc[7], ts[7];
  tw_fwd(lane, tc, ts);
  #pragma unroll
  for (int t = 0; t < 8; t++) {
    int ca = wv*16 + 2*t, cb = ca + 1;
    float lor = T[ca*130 + lane],      loi = T[cb*130 + lane];
    float hir = T[ca*130 + 64 + lane], hii = T[cb*130 + 64 + lane];
    fft128_fwd(lor, loi, hir, hii, lane, tc, ts);
    float er  = __shfl(lor, rb), ei  = __shfl(loi, rb);
    float our = __shfl(hir, rb), oui = __shfl(hii, rb);
    float per = __shfl(er, pe),  pei = __shfl(ei, pe);
    float por = __shfl(our, po), poi = __shfl(oui, po);
    float ae_r = 0.5f*(er + per),  ae_i = 0.5f*(ei - pei);
    float be_r = 0.5f*(ei + pei),  be_i = 0.5f*(per - er);
    float ao_r = 0.5f*(our + por), ao_i = 0.5f*(oui - poi);
    float bo_r = 0.5f*(oui + poi), bo_i = 0.5f*(por - our);
    if (lane == 32) { ao_r = 0.f; ao_i = 0.f; bo_r = 0.f; bo_i = 0.f; } // col 65 pad
    if (lane <= 32) {
      size_t ba = (size_t)(b*128 + ch + ca)*L2_ + (size_t)h*W2_ + 2*lane;
      size_t bb = (size_t)(b*128 + ch + cb)*L2_ + (size_t)h*W2_ + 2*lane;
      *(unsigned*)(re + ba) = (unsigned)f2b(ae_r) | ((unsigned)f2b(ao_r) << 16);
      *(unsigned*)(im + ba) = (unsigned)f2b(ae_i) | ((unsigned)f2b(ao_i) << 16);
      *(unsigned*)(re + bb) = (unsigned)f2b(be_r) | ((unsigned)f2b(bo_r) << 16);
      *(unsigned*)(im + bb) = (unsigned)f2b(be_i) | ((unsigned)f2b(bo_i) << 16);
    }
  }
}

// column FFT over half-spectrum (bf16 storage): 2 blocks per (b,c) image, 33 cols each.
__global__ __launch_bounds__(256) void k_fft_col_fwd_h(bf16_t* __restrict__ re, bf16_t* __restrict__ im) {
  __shared__ float Lre[128][34];
  __shared__ float Lim[128][34];
  int tid = threadIdx.x;
  size_t img = blockIdx.x >> 1;
  int w0 = (blockIdx.x & 1) * 33;
  bf16_t* rp = re + img * (size_t)L2_ + w0;
  bf16_t* ip = im + img * (size_t)L2_ + w0;
  for (int i = tid; i < 4224; i += 256) {
    int h = i / 33, wl = i - h*33;
    Lre[h][wl] = ldf(rp[(size_t)h*W2_ + wl]);
    Lim[h][wl] = ldf(ip[(size_t)h*W2_ + wl]);
  }
  __syncthreads();
  int lane = tid & 63, wv = tid >> 6;
  float tc[7], ts[7];
  tw_fwd(lane, tc, ts);
  for (int col = wv; col < 33; col += 4) {
    float lor = Lre[lane][col], loi = Lim[lane][col];
    float hir = Lre[lane+64][col], hii = Lim[lane+64][col];
    fft128_fwd(lor, loi, hir, hii, lane, tc, ts);
    Lre[lane][col]=lor; Lim[lane][col]=loi;
    Lre[lane+64][col]=hir; Lim[lane+64][col]=hii;
  }
  __syncthreads();
  for (int i = tid; i < 4224; i += 256) {
    int h = i / 33, wl = i - h*33;
    rp[(size_t)h*W2_ + wl] = f2b(Lre[h][wl]);
    ip[(size_t)h*W2_ + wl] = f2b(Lim[h][wl]);
  }
}

// inverse col FFT (half-spectrum, bf16 storage) with sigmoid gating fused into the load phase.
__global__ __launch_bounds__(256) void k_fft_col_inv_scaled_h(
    bf16_t* __restrict__ re, bf16_t* __restrict__ im,
    const float* __restrict__ wg1, const float* __restrict__ fw2,
    const float* __restrict__ fb2) {
  __shared__ float Lre[128][34];
  __shared__ float Lim[128][34];
  __shared__ float w2r[8];
  int tid = threadIdx.x;
  size_t img = blockIdx.x >> 1;
  int c = (int)(img & 127);
  int b = (int)(img >> 7);
  int w0 = (blockIdx.x & 1) * 33;
  if (tid < 8) w2r[tid] = fw2[c*8 + tid];
  float b2 = fb2[c];
  bf16_t* rp = re + img * (size_t)L2_ + w0;
  bf16_t* ip = im + img * (size_t)L2_ + w0;
  const float* wgp = wg1 + (size_t)b*8*L2_ + w0;
  __syncthreads();
  for (int i = tid; i < 4224; i += 256) {
    int h = i / 33, wl = i - h*33;
    size_t p = (size_t)h*W2_ + wl;
    float a = b2;
    #pragma unroll
    for (int o = 0; o < 8; o++) a += w2r[o] * wgp[(size_t)o*L2_ + p];
    float wgt = 1.f/(1.f+expf(-a));
    Lre[h][wl] = ldf(rp[p]) * wgt;
    Lim[h][wl] = ldf(ip[p]) * wgt;
  }
  __syncthreads();
  int lane = tid & 63, wv = tid >> 6;
  float tc[7], ts[7];
  tw_inv(lane, tc, ts);
  for (int col = wv; col < 33; col += 4) {
    float lor = Lre[lane][col], loi = Lim[lane][col];
    float hir = Lre[lane+64][col], hii = Lim[lane+64][col];
    fft128_inv(lor, loi, hir, hii, lane, tc, ts);
    Lre[lane][col]=lor*(1.f/128.f); Lim[lane][col]=loi*(1.f/128.f);
    Lre[lane+64][col]=hir*(1.f/128.f); Lim[lane+64][col]=hii*(1.f/128.f);
  }
  __syncthreads();
  for (int i = tid; i < 4224; i += 256) {
    int h = i / 33, wl = i - h*33;
    rp[(size_t)h*W2_ + wl] = f2b(Lre[h][wl]);
    ip[(size_t)h*W2_ + wl] = f2b(Lim[h][wl]);
  }
}

// inverse row FFT from half-spectrum (bf16 storage; 2 real channels per complex IFFT)
// + abs+bn+relu + transpose to seq with fused residual adds (add1 fp32, add2 bf16).
// out may alias add1.
__global__ __launch_bounds__(256) void k_fft_row_inv_abs_seq_h(
    const bf16_t* __restrict__ re, const bf16_t* __restrict__ im,
    const float* __restrict__ ng, const float* __restrict__ nbe,
    const float* __restrict__ add1, const bf16_t* __restrict__ add2,
    float* __restrict__ out) {
  __shared__ float S[64*132];   // phase A/B: spectra ; phase C/D: T[64*130]
  int tid = threadIdx.x;
  int bid = blockIdx.x;
  int ch = (bid & 1) * 64;
  int h  = (bid >> 1) & 127;
  int b  = bid >> 8;
  {
    const bf16_t* rbase = re + (size_t)(b*128 + ch)*L2_ + (size_t)h*W2_;
    const bf16_t* ibase = im + (size_t)(b*128 + ch)*L2_ + (size_t)h*W2_;
    for (int i = tid; i < 64*66; i += 256) {
      int c = i / 66, v = i - c*66;
      S[c*132 + v]      = ldf(rbase[(size_t)c*L2_ + v]);
      S[c*132 + 66 + v] = ldf(ibase[(size_t)c*L2_ + v]);
    }
  }
  __syncthreads();
  int lane = tid & 63, wv = tid >> 6;
  int rb = (int)(__brev((unsigned)lane) >> 26);
  int vlo = 2*rb, vhi = vlo + 1;
  float tc[7], ts[7];
  tw_inv(lane, tc, ts);
  float rr[8][4];
  #pragma unroll
  for (int t = 0; t < 8; t++) {
    int ca = wv*16 + 2*t, cb = ca + 1;
    const float* Sa = S + ca*132;
    const float* Sb = S + cb*132;
    float lor, loi, hir, hii;
    if (vlo <= 64) {
      float ar = Sa[vlo], ai = Sa[66+vlo], br = Sb[vlo], bi = Sb[66+vlo];
      lor = ar - bi; loi = ai + br;
    } else {
      int u = 128 - vlo;
      float ar = Sa[u], ai = Sa[66+u], br = Sb[u], bi = Sb[66+u];
      lor = ar + bi; loi = br - ai;
    }
    if (vhi <= 64) {
      float ar = Sa[vhi], ai = Sa[66+vhi], br = Sb[vhi], bi = Sb[66+vhi];
      hir = ar - bi; hii = ai + br;
    } else {
      int u = 128 - vhi;
      float ar = Sa[u], ai = Sa[66+u], br = Sb[u], bi = Sb[66+u];
      hir = ar + bi; hii = br - ai;
    }
    fft128_inv(lor, loi, hir, hii, lane, tc, ts);
    rr[t][0] = fabsf(lor);
    rr[t][1] = fabsf(loi);
    rr[t][2] = fabsf(hir);
    rr[t][3] = fabsf(hii);
  }
  __syncthreads();
  float* T = S;
  #pragma unroll
  for (int t = 0; t < 8; t++) {
    int ca = wv*16 + 2*t, cb = ca + 1;
    float sga = ng[ch+ca]*BN_INV, sba = nbe[ch+ca];
    float sgb = ng[ch+cb]*BN_INV, sbb = nbe[ch+cb];
    T[ca*130 + lane]      = fmaxf(rr[t][0]*(1.f/128.f)*sga + sba, 0.f);
    T[cb*130 + lane]      = fmaxf(rr[t][1]*(1.f/128.f)*sgb + sbb, 0.f);
    T[ca*130 + 64 + lane] = fmaxf(rr[t][2]*(1.f/128.f)*sga + sba, 0.f);
    T[cb*130 + 64 + lane] = fmaxf(rr[t][3]*(1.f/128.f)*sgb + sbb, 0.f);
  }
  __syncthreads();
  size_t sb0 = ((size_t)b*L_ + (size_t)h*128)*128 + ch;
  #pragma unroll
  for (int it = 0; it < 8; it++) {
    int idx = it*256 + tid;
    int c4 = (idx & 15)*4, w = idx >> 4;
    size_t off = sb0 + (size_t)w*128 + c4;
    float4 v;
    v.x = T[(c4+0)*130 + w];
    v.y = T[(c4+1)*130 + w];
    v.z = T[(c4+2)*130 + w];
    v.w = T[(c4+3)*130 + w];
    float4 x1 = *(const float4*)(add1 + off);
    uint2 q2 = *(const uint2*)(add2 + off);
    v.x += x1.x + ldf((bf16_t)(q2.x & 0xffffu));
    v.y += x1.y + ldf((bf16_t)(q2.x >> 16));
    v.z += x1.z + ldf((bf16_t)(q2.y & 0xffffu));
    v.w += x1.w + ldf((bf16_t)(q2.y >> 16));
    *(float4*)(out + off) = v;
  }
}

// ---------------------------------------------------------------- freq hidden (8ch) conv, half-plane (bf16 spectrum in)
__global__ __launch_bounds__(256) void k_freq1_h(const bf16_t* __restrict__ tre,
    const float* __restrict__ fw1, const float* __restrict__ fb1,
    const float* __restrict__ fg, const float* __restrict__ fbe,
    float* __restrict__ wg1) {
  __shared__ float w1s[1024];
  int tid = threadIdx.x;
  for (int i = tid; i < 1024; i += 256) w1s[i] = fw1[i];
  __syncthreads();
  size_t g = (size_t)blockIdx.x*256 + tid;   // (b,p) over B*L2_
  int p = (int)(g % L2_);
  int b = (int)(g / L2_);
  const bf16_t* tp = tre + (size_t)b*128*L2_ + p;
  float acc[8];
  #pragma unroll
  for (int o = 0; o < 8; o++) acc[o] = 0.f;
  for (int c = 0; c < 128; c++) {
    float v = ldf(tp[(size_t)c*L2_]);
    #pragma unroll
    for (int o = 0; o < 8; o++) acc[o] += w1s[o*128+c]*v;
  }
  size_t ob = (size_t)b*8*L2_ + p;
  #pragma unroll
  for (int o = 0; o < 8; o++) {
    float v = (acc[o] + fb1[o]) * (fg[o]*BN_INV) + fbe[o];
    wg1[ob + (size_t)o*L2_] = fmaxf(v, 0.f);
  }
}

// ---------------------------------------------------------------- planar->seq transpose (bf16 out)
template<bool DUAL>
__global__ void k_p2s(const void* __restrict__ src, bf16_t* __restrict__ dst,
                      const int* __restrict__ flagp) {
  __shared__ float tile[32][33];
  int fl = DUAL ? *flagp : 1;
  int b = blockIdx.z;
  int p0 = blockIdx.x*32, c0 = blockIdx.y*32;
  int tx = threadIdx.x, ty = threadIdx.y;
  size_t base_in = (size_t)b*NSP;
  #pragma unroll
  for (int k = 0; k < 4; k++) {
    size_t off = base_in + (size_t)(c0+ty+8*k)*L_ + p0 + tx;
    float v;
    if (DUAL && !fl) v = ldf(((const bf16_t*)src)[off]);
    else             v = ((const float*)src)[off];
    tile[ty+8*k][tx] = v;
  }
  __syncthreads();
  size_t base = (size_t)b*NSP;
  #pragma unroll
  for (int k = 0; k < 4; k++) {
    size_t idx = base + (size_t)(p0+ty+8*k)*C_ + c0 + tx;
    dst[idx] = f2b(tile[tx][ty+8*k]);
  }
}

// ---------------------------------------------------------------- depthwise 3x3 (NHWC), residual add; IN16: bf16 input
template<int CC, bool IN16>  // out = in + dw + b (out fp32)
__global__ __launch_bounds__(256) void k_dw3(const void* __restrict__ in_,
    const float* __restrict__ w, const float* __restrict__ bias,
    float* __restrict__ out) {
  __shared__ float wl[9*CC];
  int tid = threadIdx.x;
  for (int i = tid; i < 9*CC; i += 256) {
    int tap = i / CC, ch = i % CC;
    wl[i] = w[ch*9 + tap];
  }
  __syncthreads();
  size_t g = (size_t)blockIdx.x*256 + tid;
  int c = (int)(g & (CC-1));
  float wr[9];
  #pragma unroll
  for (int t = 0; t < 9; t++) wr[t] = wl[t*CC + c];
  size_t s = g / CC;
  int w0 = (int)(s & 31) * 4;
  int hp = (int)((s >> 5) & 127);
  int b  = (int)(s >> 12);
  size_t ibase = (size_t)b*L_*CC + c;
  float bi = bias[c];
  float a0 = bi, a1 = bi, a2 = bi, a3 = bi;
  #pragma unroll
  for (int dh = -1; dh <= 1; dh++) {
    int h2 = hp + dh;
    if ((unsigned)h2 >= 128u) continue;
    size_t rbase = ibase + (size_t)h2*W_*CC;
    float px[6];
    #pragma unroll
    for (int x = 0; x < 6; x++) {
      int w2 = w0 - 1 + x;
      if ((unsigned)w2 < 128u) {
        px[x] = IN16 ? ldf(((const bf16_t*)in_)[rbase + (size_t)w2*CC])
                     : ((const float*)in_)[rbase + (size_t)w2*CC];
      } else px[x] = 0.f;
    }
    #pragma unroll
    for (int dw = 0; dw < 3; dw++) {
      float f = wr[(dh+1)*3 + dw];
      a0 += f*px[dw];   a1 += f*px[dw+1];
      a2 += f*px[dw+2]; a3 += f*px[dw+3];
    }
  }
  size_t tb = (size_t)b*L_ + (size_t)hp*W_ + w0;
  float r0 = IN16 ? ldf(((const bf16_t*)in_)[(tb+0)*CC + c]) : ((const float*)in_)[(tb+0)*CC + c];
  float r1 = IN16 ? ldf(((const bf16_t*)in_)[(tb+1)*CC + c]) : ((const float*)in_)[(tb+1)*CC + c];
  float r2 = IN16 ? ldf(((const bf16_t*)in_)[(tb+2)*CC + c]) : ((const float*)in_)[(tb+2)*CC + c];
  float r3 = IN16 ? ldf(((const bf16_t*)in_)[(tb+3)*CC + c]) : ((const float*)in_)[(tb+3)*CC + c];
  out[(tb+0)*CC + c] = r0 + a0;
  out[(tb+1)*CC + c] = r1 + a1;
  out[(tb+2)*CC + c] = r2 + a2;
  out[(tb+3)*CC + c] = r3 + a3;
}

// ---------------------------------------------------------------- depthwise 3x3, 64ch, silu, bf16 in/out
__global__ __launch_bounds__(256) void k_dw3h(const bf16_t* __restrict__ in,
    const float* __restrict__ w, const float* __restrict__ bias,
    bf16_t* __restrict__ out) {
  __shared__ float wl[9*64];
  int tid = threadIdx.x;
  for (int i = tid; i < 9*64; i += 256) {
    int tap = i / 64, ch = i % 64;
    wl[i] = w[ch*9 + tap];
  }
  __syncthreads();
  size_t g = (size_t)blockIdx.x*256 + tid;
  int c = (int)(g & 63);
  float wr[9];
  #pragma unroll
  for (int t = 0; t < 9; t++) wr[t] = wl[t*64 + c];
  size_t s = g >> 6;
  int w0 = (int)(s & 31) * 4;
  int hp = (int)((s >> 5) & 127);
  int b  = (int)(s >> 12);
  const bf16_t* ip = in + (size_t)b*L_*64 + c;
  float bi = bias[c];
  float a0 = bi, a1 = bi, a2 = bi, a3 = bi;
  #pragma unroll
  for (int dh = -1; dh <= 1; dh++) {
    int h2 = hp + dh;
    if ((unsigned)h2 >= 128u) continue;
    const bf16_t* rp = ip + (size_t)h2*W_*64;
    float px[6];
    #pragma unroll
    for (int x = 0; x < 6; x++) {
      int w2 = w0 - 1 + x;
      px[x] = ((unsigned)w2 < 128u) ? ldf(rp[(size_t)w2*64]) : 0.f;
    }
    #pragma unroll
    for (int dw = 0; dw < 3; dw++) {
      float f = wr[(dh+1)*3 + dw];
      a0 += f*px[dw];   a1 += f*px[dw+1];
      a2 += f*px[dw+2]; a3 += f*px[dw+3];
    }
  }
  size_t tb = (size_t)b*L_ + (size_t)hp*W_ + w0;
  out[(tb+0)*64 + c] = f2b(a0 / (1.f + expf(-a0)));
  out[(tb+1)*64 + c] = f2b(a1 / (1.f + expf(-a1)));
  out[(tb+2)*64 + c] = f2b(a2 / (1.f + expf(-a2)));
  out[(tb+3)*64 + c] = f2b(a3 / (1.f + expf(-a3)));
}

// ---------------------------------------------------------------- grouped conv KxK (bf16 in/out), 4 pixels/thread
template<int K>
__global__ __launch_bounds__(256) void k_gconv(const bf16_t* __restrict__ in,
    const float* __restrict__ w, bf16_t* __restrict__ out) {
  __shared__ float wl[K*K*128];
  int tid = threadIdx.x;
  for (int i = tid; i < 128*K*K; i += 256) {
    int tap = i >> 7, ch = i & 127;
    wl[i] = w[ch*(K*K) + tap];
  }
  __syncthreads();
  size_t g = (size_t)blockIdx.x*256 + tid;
  int oc = (int)(g & 63);
  float wx[K*K], wy[K*K];
  #pragma unroll
  for (int t = 0; t < K*K; t++) {
    wx[t] = wl[t*128 + 2*oc];
    wy[t] = wl[t*128 + 2*oc + 1];
  }
  size_t s = g >> 6;
  int w0 = (int)(s & 31) * 4;
  int hp = (int)((s >> 5) & 127);
  int b  = (int)(s >> 12);
  const bf16_t* ip = in + (size_t)b*L_*128 + 2*oc;
  constexpr int P = K/2;
  float a0 = 0.f, a1 = 0.f, a2 = 0.f, a3 = 0.f;
  #pragma unroll
  for (int kh = 0; kh < K; kh++) {
    int h2 = hp + kh - P;
    if ((unsigned)h2 >= 128u) continue;
    const bf16_t* rp = ip + (size_t)h2*W_*128;
    float2 px[K+3];
    #pragma unroll
    for (int x = 0; x < K+3; x++) {
      int w2 = w0 - P + x;
      if ((unsigned)w2 < 128u) {
        unsigned uv = *(const unsigned*)(rp + (size_t)w2*128);
        px[x] = make_float2(ldf((bf16_t)(uv & 0xffffu)), ldf((bf16_t)(uv >> 16)));
      } else px[x] = make_float2(0.f, 0.f);
    }
    #pragma unroll
    for (int kw = 0; kw < K; kw++) {
      float fx = wx[kh*K + kw], fy = wy[kh*K + kw];
      a0 += fx*px[kw+0].x + fy*px[kw+0].y;
      a1 += fx*px[kw+1].x + fy*px[kw+1].y;
      a2 += fx*px[kw+2].x + fy*px[kw+2].y;
      a3 += fx*px[kw+3].x + fy*px[kw+3].y;
    }
  }
  size_t tb = (size_t)b*L_ + (size_t)hp*W_ + w0;
  out[(tb+0)*64 + oc] = f2b(a0);
  out[(tb+1)*64 + oc] = f2b(a1);
  out[(tb+2)*64 + oc] = f2b(a2);
  out[(tb+3)*64 + oc] = f2b(a3);
}

// ---------------------------------------------------------------- MFMA token GEMM (seq, bf16 W from global)
// IB16: 'in' bf16 (direct fragments). MUL: elementwise mul by bf16 mulp. OB16: bf16 output.
template<int CIN, int COUT, int EPI, bool MUL, bool IB16, bool OB16>   // EPI 0:none 1:bias 2:bias+silu 3:bias+elu+1
__global__ __launch_bounds__(256) void k_mfma_tok(
    const void* __restrict__ in, const bf16_t* __restrict__ mulp,
    const bf16_t* __restrict__ W16, const float* __restrict__ bias,
    void* __restrict__ out) {
  constexpr int NO = COUT/16;
  constexpr int KS = (CIN >= 128) ? 4 : (CIN/32);
  int tid = threadIdx.x;
  int lane = tid & 63, wv = tid >> 6;
  int m = lane & 15, q = lane >> 4;
  size_t t0 = (size_t)blockIdx.x*64 + (size_t)wv*16;
  f32x4 acc[NO];
  #pragma unroll
  for (int i = 0; i < NO; i++) acc[i] = (f32x4){0.f,0.f,0.f,0.f};
  for (int kc = 0; kc < CIN; kc += KS*32) {
    short8 afv[KS];
    if (IB16) {
      #pragma unroll
      for (int kk = 0; kk < KS; kk++) {
        short8 a = *(const short8*)((const bf16_t*)in + (t0 + m)*CIN + kc + kk*32 + q*8);
        if (MUL) {
          short8 mz = *(const short8*)(mulp + (t0 + m)*CIN + kc + kk*32 + q*8);
          union { short s[8]; short8 v; } ua, um, ur;
          ua.v = a; um.v = mz;
          #pragma unroll
          for (int j = 0; j < 8; j++)
            ur.s[j] = (short)f2b(ldf((bf16_t)ua.s[j]) * ldf((bf16_t)um.s[j]));
          afv[kk] = ur.v;
        } else afv[kk] = a;
      }
    } else {
      float4 A[KS][2];
      #pragma unroll
      for (int kk = 0; kk < KS; kk++) {
        const float* ap = (const float*)in + (t0 + m)*CIN + kc + kk*32 + q*8;
        A[kk][0] = *(const float4*)ap;
        A[kk][1] = *(const float4*)(ap + 4);
      }
      #pragma unroll
      for (int kk = 0; kk < KS; kk++) {
        union { short s[8]; short8 v; } af;
        af.s[0]=(short)f2b(A[kk][0].x); af.s[1]=(short)f2b(A[kk][0].y);
        af.s[2]=(short)f2b(A[kk][0].z); af.s[3]=(short)f2b(A[kk][0].w);
        af.s[4]=(short)f2b(A[kk][1].x); af.s[5]=(short)f2b(A[kk][1].y);
        af.s[6]=(short)f2b(A[kk][1].z); af.s[7]=(short)f2b(A[kk][1].w);
        afv[kk] = af.v;
      }
    }
    #pragma unroll
    for (int kk = 0; kk < KS; kk++) {
      #pragma unroll
      for (int o = 0; o < NO; o++) {
        short8 bf = *(const short8*)(W16 + (size_t)(o*16 + m)*CIN + kc + kk*32 + q*8);
        acc[o] = __builtin_amdgcn_mfma_f32_16x16x32_bf16(afv[kk], bf, acc[o], 0, 0, 0);
      }
    }
  }
  #pragma unroll
  for (int o = 0; o < NO; o++) {
    float bv = (EPI >= 1) ? bias[o*16 + m] : 0.f;
    #pragma unroll
    for (int r = 0; r < 4; r++) {
      int row = q*4 + r;
      float v = acc[o][r] + bv;
      if (EPI == 2) v = v / (1.f + expf(-v));
      if (EPI == 3) v = v > 0.f ? v + 1.f : expf(v);
      size_t idx = (t0 + row)*COUT + o*16 + m;
      if (OB16) ((bf16_t*)out)[idx] = f2b(v);
      else      ((float*)out)[idx] = v;
    }
  }
}

// ---------------------------------------------------------------- fused LN + 3 GEMMs (d3w1, d5w1, ap)
// combined 24-accumulator GEMM; bf16 outputs staged via LDS for coalesced 16B stores.
__global__ __launch_bounds__(256) void k_mfma_ln3(
    const float* __restrict__ in,
    const float* __restrict__ lng, const float* __restrict__ lnb,
    const bf16_t* __restrict__ Wd3, const float* __restrict__ bd3,
    const bf16_t* __restrict__ Wd5, const float* __restrict__ bd5,
    const bf16_t* __restrict__ Wap, const float* __restrict__ bap,
    bf16_t* __restrict__ outd3, bf16_t* __restrict__ outd5, bf16_t* __restrict__ outap) {
  __shared__ float gs[128], bs[128];
  __shared__ bf16_t T16[64*130];
  int tid = threadIdx.x;
  if (tid < 128) { gs[tid] = lng[tid]; bs[tid] = lnb[tid]; }
  __syncthreads();
  int lane = tid & 63, wv = tid >> 6;
  int m = lane & 15, q = lane >> 4;
  size_t t0 = (size_t)blockIdx.x*64 + (size_t)wv*16;
  size_t t0blk = (size_t)blockIdx.x*64;
  float4 A[4][2];
  #pragma unroll
  for (int kk = 0; kk < 4; kk++) {
    const float* ap = in + (t0 + m)*128 + kk*32 + q*8;
    A[kk][0] = *(const float4*)ap;
    A[kk][1] = *(const float4*)(ap + 4);
  }
  float s = 0.f, ss = 0.f;
  #pragma unroll
  for (int kk = 0; kk < 4; kk++)
    #pragma unroll
    for (int h = 0; h < 2; h++) {
      float4 v = A[kk][h];
      s  += v.x + v.y + v.z + v.w;
      ss += v.x*v.x + v.y*v.y + v.z*v.z + v.w*v.w;
    }
  s  += __shfl_xor(s, 16);  s  += __shfl_xor(s, 32);
  ss += __shfl_xor(ss, 16); ss += __shfl_xor(ss, 32);
  float mean = s*(1.f/128.f);
  float inv = rsqrtf(ss*(1.f/128.f) - mean*mean + 1e-5f);
  short8 af[4];
  #pragma unroll
  for (int kk = 0; kk < 4; kk++) {
    union { short sh[8]; short8 v; } u;
    #pragma unroll
    for (int h = 0; h < 2; h++) {
      const float* vp = (const float*)&A[kk][h];
      #pragma unroll
      for (int j = 0; j < 4; j++) {
        int c = kk*32 + q*8 + h*4 + j;
        float x = (vp[j] - mean)*inv*gs[c] + bs[c];
        u.sh[h*4+j] = (short)f2b(x);
      }
    }
    af[kk] = u.v;
  }
  f32x4 acc[24];
  #pragma unroll
  for (int i = 0; i < 24; i++) acc[i] = (f32x4){0.f,0.f,0.f,0.f};
  #pragma unroll
  for (int kk = 0; kk < 4; kk++) {
    #pragma unroll
    for (int o = 0; o < 8; o++) {
      size_t woff = (size_t)(o*16 + m)*128 + kk*32 + q*8;
      short8 b3 = *(const short8*)(Wd3 + woff);
      acc[o]    = __builtin_amdgcn_mfma_f32_16x16x32_bf16(af[kk], b3, acc[o],    0, 0, 0);
      short8 b5 = *(const short8*)(Wd5 + woff);
      acc[8+o]  = __builtin_amdgcn_mfma_f32_16x16x32_bf16(af[kk], b5, acc[8+o],  0, 0, 0);
      short8 ba = *(const short8*)(Wap + woff);
      acc[16+o] = __builtin_amdgcn_mfma_f32_16x16x32_bf16(af[kk], ba, acc[16+o], 0, 0, 0);
    }
  }
  #pragma unroll
  for (int mi = 0; mi < 3; mi++) {
    const float* bp = (mi == 0) ? bd3 : (mi == 1) ? bd5 : bap;
    bf16_t* op = (mi == 0) ? outd3 : (mi == 1) ? outd5 : outap;
    #pragma unroll
    for (int o = 0; o < 8; o++) {
      float bv = bp[o*16 + m];
      #pragma unroll
      for (int r = 0; r < 4; r++) {
        float v = acc[mi*8 + o][r] + bv;
        if (mi == 2) v = v / (1.f + expf(-v));
        T16[(wv*16 + q*4 + r)*130 + o*16 + m] = f2b(v);
      }
    }
    __syncthreads();
    for (int i = tid; i < 1024; i += 256) {
      int tok = i >> 4, c0 = (i & 15) * 8;
      union { bf16_t u[8]; short8 v; } pk;
      #pragma unroll
      for (int j = 0; j < 8; j++) pk.u[j] = T16[tok*130 + c0 + j];
      *(short8*)(op + (t0blk + tok)*128 + c0) = pk.v;
    }
    __syncthreads();
  }
}

// ---------------------------------------------------------------- MFMA c1: bf16 seq in -> relu(bn(conv1x1)) -> bf16 seq out
__global__ __launch_bounds__(256) void k_mfma_c1(
    const bf16_t* __restrict__ in, const bf16_t* __restrict__ W16,
    const float* __restrict__ bias, const float* __restrict__ gam,
    const float* __restrict__ bet, bf16_t* __restrict__ out) {
  __shared__ bf16_t T16[64*130];
  constexpr int NO = 8;
  int tid = threadIdx.x;
  int lane = tid & 63, wv = tid >> 6;
  int m = lane & 15, q = lane >> 4;
  size_t t0 = (size_t)blockIdx.x*64 + (size_t)wv*16;
  size_t t0blk = (size_t)blockIdx.x*64;
  f32x4 acc[NO];
  #pragma unroll
  for (int i = 0; i < NO; i++) acc[i] = (f32x4){0.f,0.f,0.f,0.f};
  #pragma unroll
  for (int kk = 0; kk < 4; kk++) {
    short8 afv = *(const short8*)(in + (t0 + m)*128 + kk*32 + q*8);
    #pragma unroll
    for (int o = 0; o < NO; o++) {
      short8 bf = *(const short8*)(W16 + (size_t)(o*16 + m)*128 + kk*32 + q*8);
      acc[o] = __builtin_amdgcn_mfma_f32_16x16x32_bf16(afv, bf, acc[o], 0, 0, 0);
    }
  }
  #pragma unroll
  for (int o = 0; o < NO; o++) {
    int oc = o*16 + m;
    float bi = bias[oc], gm = gam[oc]*BN_INV, be = bet[oc];
    #pragma unroll
    for (int r = 0; r < 4; r++) {
      float v = acc[o][r] + bi;
      T16[(wv*16 + q*4 + r)*130 + oc] = f2b(fmaxf(v*gm + be, 0.f));
    }
  }
  __syncthreads();
  for (int i = tid; i < 1024; i += 256) {
    int tok = i >> 4, c0 = (i & 15) * 8;
    union { bf16_t u[8]; short8 v; } pk;
    #pragma unroll
    for (int j = 0; j < 8; j++) pk.u[j] = T16[tok*130 + c0 + j];
    *(short8*)(out + (t0blk + tok)*128 + c0) = pk.v;
  }
}

// ---------------------------------------------------------------- MFMA red (po folded in):
// out = relu(bn(R0@x0 + (R1@Wpo)@xt4)) + x0; x0 seq is bf16; planar out via LDS transpose.
__global__ __launch_bounds__(256) void k_mfma_red(
    const bf16_t* __restrict__ x0s, const float* __restrict__ xt4,
    const bf16_t* __restrict__ W16, const float* __restrict__ bias,
    const float* __restrict__ gam, const float* __restrict__ bet,
    void* __restrict__ out, const int* __restrict__ flagp) {
  __shared__ float T[128*65];
  constexpr int NO = 8;
  int fl = *flagp;
  int tid = threadIdx.x;
  int lane = tid & 63, wv = tid >> 6;
  int m = lane & 15, q = lane >> 4;
  size_t t0 = (size_t)blockIdx.x*64;
  size_t tw = t0 + (size_t)wv*16;
  f32x4 acc[NO];
  #pragma unroll
  for (int i = 0; i < NO; i++) acc[i] = (f32x4){0.f,0.f,0.f,0.f};
  // half 0: x0 (bf16, direct fragments)
  #pragma unroll
  for (int kk = 0; kk < 4; kk++) {
    short8 afv = *(const short8*)(x0s + (tw + m)*128 + kk*32 + q*8);
    #pragma unroll
    for (int o = 0; o < NO; o++) {
      short8 bf = *(const short8*)(W16 + (size_t)(o*16 + m)*256 + kk*32 + q*8);
      acc[o] = __builtin_amdgcn_mfma_f32_16x16x32_bf16(afv, bf, acc[o], 0, 0, 0);
    }
  }
  // half 1: xt4 (fp32 -> bf16)
  {
    float4 A[4][2];
    #pragma unroll
    for (int kk = 0; kk < 4; kk++) {
      const float* ap = xt4 + (tw + m)*128 + kk*32 + q*8;
      A[kk][0] = *(const float4*)ap;
      A[kk][1] = *(const float4*)(ap + 4);
    }
    #pragma unroll
    for (int kk = 0; kk < 4; kk++) {
      union { short s[8]; short8 v; } af;
      af.s[0]=(short)f2b(A[kk][0].x); af.s[1]=(short)f2b(A[kk][0].y);
      af.s[2]=(short)f2b(A[kk][0].z); af.s[3]=(short)f2b(A[kk][0].w);
      af.s[4]=(short)f2b(A[kk][1].x); af.s[5]=(short)f2b(A[kk][1].y);
      af.s[6]=(short)f2b(A[kk][1].z); af.s[7]=(short)f2b(A[kk][1].w);
      #pragma unroll
      for (int o = 0; o < NO; o++) {
        short8 bf = *(const short8*)(W16 + (size_t)(o*16 + m)*256 + 128 + kk*32 + q*8);
        acc[o] = __builtin_amdgcn_mfma_f32_16x16x32_bf16(af.v, bf, acc[o], 0, 0, 0);
      }
    }
  }
  #pragma unroll
  for (int ot = 0; ot < NO; ot++) {
    int o = ot*16 + m;
    float bi = bias[o], gm = gam[o]*BN_INV, be = bet[o];
    #pragma unroll
    for (int r = 0; r < 4; r++) {
      int row = q*4 + r;
      float v = acc[ot][r] + bi;
      v = fmaxf(v*gm + be, 0.f);
      v += ldf(x0s[(tw + row)*128 + o]);
      T[o*65 + wv*16 + row] = v;
    }
  }
  __syncthreads();
  int b = (int)(t0 >> 14);
  int p0 = (int)(t0 & (L_-1));
  if (!fl) {
    bf16_t* op = (bf16_t*)out;
    for (int i = tid; i < 8192; i += 256) {
      int o = i >> 6, tk = i & 63;
      op[((size_t)b*128 + o)*L_ + p0 + tk] = f2b(T[o*65 + tk]);
    }
  } else {
    float* op = (float*)out;
    for (int i = tid; i < 8192; i += 256) {
      int o = i >> 6, tk = i & 63;
      op[((size_t)b*128 + o)*L_ + p0 + tk] = T[o*65 + tk];
    }
  }
}

// ---------------------------------------------------------------- LN+FFN (bf16 out)
__global__ __launch_bounds__(256) void k_ln_ffn(const float* __restrict__ in,
    const float* __restrict__ g, const float* __restrict__ be,
    const float* __restrict__ w1, const float* __restrict__ b1,
    const float* __restrict__ w2, const float* __restrict__ b2,
    bf16_t* __restrict__ out) {
  int tid = threadIdx.x, lane = tid & 63;
  size_t t = (size_t)blockIdx.x*4 + (tid >> 6);
  const float* row = in + t*128;
  float2 v = *(const float2*)(row + lane*2);
  float s = v.x + v.y, ss = v.x*v.x + v.y*v.y;
  #pragma unroll
  for (int m = 1; m < 64; m <<= 1) { s += __shfl_xor(s, m); ss += __shfl_xor(ss, m); }
  float mean = s*(1.f/128.f);
  float inv = rsqrtf(ss*(1.f/128.f) - mean*mean + 1e-5f);
  float hx = (v.x-mean)*inv*g[lane*2]   + be[lane*2];
  float hy = (v.y-mean)*inv*g[lane*2+1] + be[lane*2+1];
  float hp0 = hx*w1[0*128+lane*2] + hy*w1[0*128+lane*2+1];
  float hp1 = hx*w1[1*128+lane*2] + hy*w1[1*128+lane*2+1];
  float hp2 = hx*w1[2*128+lane*2] + hy*w1[2*128+lane*2+1];
  float hp3 = hx*w1[3*128+lane*2] + hy*w1[3*128+lane*2+1];
  #pragma unroll
  for (int m = 1; m < 64; m <<= 1) {
    hp0 += __shfl_xor(hp0, m); hp1 += __shfl_xor(hp1, m);
    hp2 += __shfl_xor(hp2, m); hp3 += __shfl_xor(hp3, m);
  }
  float hv0, hv1, hv2, hv3;
  { float a = hp0 + b1[0]; hv0 = 0.5f*a*(1.f+erff(a*0.7071067811865476f)); }
  { float a = hp1 + b1[1]; hv1 = 0.5f*a*(1.f+erff(a*0.7071067811865476f)); }
  { float a = hp2 + b1[2]; hv2 = 0.5f*a*(1.f+erff(a*0.7071067811865476f)); }
  { float a = hp3 + b1[3]; hv3 = 0.5f*a*(1.f+erff(a*0.7071067811865476f)); }
  int cx = lane*2, cy = lane*2+1;
  float ox = hv0*w2[cx*4+0] + hv1*w2[cx*4+1] + hv2*w2[cx*4+2] + hv3*w2[cx*4+3] + b2[cx];
  float oy = hv0*w2[cy*4+0] + hv1*w2[cy*4+1] + hv2*w2[cy*4+2] + hv3*w2[cy*4+3] + b2[cy];
  unsigned pk = (unsigned)f2b(ox) | ((unsigned)f2b(oy) << 16);
  *(unsigned*)(out + t*128 + lane*2) = pk;
}

// ---------------------------------------------------------------- linear attention (qk, v, x all bf16; CAT out bf16)
__global__ __launch_bounds__(256) void k_kv(
    const bf16_t* __restrict__ qk, const bf16_t* __restrict__ v,
    float* __restrict__ akv_g, float* __restrict__ aks_g) {
  __shared__ float kvred[512];
  __shared__ float ksred[64];
  int tid = threadIdx.x;
  for (int i = tid; i < 512; i += 256) kvred[i] = 0.f;
  if (tid < 64) ksred[tid] = 0.f;
  __syncthreads();
  int lane = tid & 63, wv = tid >> 6;
  size_t t0 = (size_t)blockIdx.x * 64;
  int b = (int)(t0 >> 14);
  int pr = lane >> 1;
  float theta = exp2f(-(float)(pr & 15) * THETA_SC);
  bool use_i = pr < 16;
  int hbase = lane & 56;
  float akv[8];
  #pragma unroll
  for (int d = 0; d < 8; d++) akv[d] = 0.f;
  float aks = 0.f;
  for (int it = 0; it < 16; it++) {
    size_t t = t0 + (size_t)wv*16 + it;
    float k = ldf(qk[t*128 + 64 + lane]);
    float xv = ldf(v[t*64 + lane]);
    int l = (int)(t & (L_-1));
    float pos = use_i ? (float)(l >> 7) : (float)(l & 127);
    float sn, cs; sincosf(pos*theta, &sn, &cs);
    float kp = __shfl_xor(k, 1);
    float kr = (lane & 1) ? (sn*kp + cs*k) : (cs*k - sn*kp);
    #pragma unroll
    for (int d = 0; d < 8; d++) {
      float krd = __shfl(kr, hbase + d);
      akv[d] += krd * xv;
    }
    aks += k;
  }
  int h8 = lane >> 3, e = lane & 7;
  #pragma unroll
  for (int d = 0; d < 8; d++)
    atomicAdd(&kvred[h8*64 + d*8 + e], akv[d]);
  atomicAdd(&ksred[lane], aks);
  __syncthreads();
  for (int i = tid; i < 512; i += 256) atomicAdd(&akv_g[b*512 + i], kvred[i]);
  if (tid < 64) atomicAdd(&aks_g[b*64 + tid], ksred[tid]);
}

__global__ __launch_bounds__(256) void k_attn2(
    const bf16_t* __restrict__ qk, const bf16_t* __restrict__ x,
    const float* __restrict__ akv_g, const float* __restrict__ aks_g,
    const float* __restrict__ lw, const float* __restrict__ lb,
    bf16_t* __restrict__ out, int coff) {
  __shared__ float kv[512];
  __shared__ float km[64];
  __shared__ float lwl[576];
  int tid = threadIdx.x;
  size_t t0 = (size_t)blockIdx.x * 32;
  int b = (int)(t0 >> 14);
  const float invn = 1.f/16384.f;
  for (int i = tid; i < 512; i += 256) kv[i] = akv_g[b*512 + i]*invn;
  if (tid < 64) km[tid] = aks_g[b*64 + tid]*invn;
  for (int i = tid; i < 576; i += 256) lwl[i] = lw[i];
  __syncthreads();
  int lane = tid & 63, wv = tid >> 6;
  int pr = lane >> 1;
  float theta = exp2f(-(float)(pr & 15) * THETA_SC);
  bool use_i = pr < 16;
  int hbase = lane & 56, e = lane & 7;
  float lbv = lb[lane];
  const bf16_t* xb = x + ((size_t)b << 14) * 64;
  for (int it = 0; it < 8; it++) {
    size_t t = t0 + (size_t)wv*8 + it;
    int l = (int)(t & (L_-1));
    int ipos = l >> 7, jpos = l & 127;
    float q = ldf(qk[t*128 + lane]);
    float p = q * km[lane];
    p += __shfl_xor(p, 1); p += __shfl_xor(p, 2); p += __shfl_xor(p, 4);
    float z = 1.f/(p + 1e-6f);
    float pos = use_i ? (float)ipos : (float)jpos;
    float sn, cs; sincosf(pos*theta, &sn, &cs);
    float qp = __shfl_xor(q, 1);
    float qr = (lane & 1) ? (sn*qp + cs*q) : (cs*q - sn*qp);
    float acc = 0.f;
    #pragma unroll
    for (int d = 0; d < 8; d++) {
      float qrd = __shfl(qr, hbase + d);
      acc += qrd * kv[hbase*8 + d*8 + e];
    }
    acc *= z;
    float lp = lbv;
    #pragma unroll
    for (int dh = -1; dh <= 1; dh++) {
      int h2 = ipos + dh; if ((unsigned)h2 >= 128u) continue;
      #pragma unroll
      for (int dw = -1; dw <= 1; dw++) {
        int w2 = jpos + dw; if ((unsigned)w2 >= 128u) continue;
        lp += lwl[lane*9 + (dh+1)*3 + (dw+1)] * ldf(xb[((size_t)(h2 << 7) + w2)*64 + lane]);
      }
    }
    out[t*128 + coff + lane] = f2b(acc + lp);
  }
}

// ---------------------------------------------------------------- launcher
extern "C" void kernel_launch(void* const* d_in, const int* in_sizes, int n_in,
                              void* d_out, int out_size, void* d_ws, size_t ws_size,
                              hipStream_t stream) {
  (void)in_sizes; (void)n_in; (void)out_size;

  float* base;
  if (ws_size >= WSF * sizeof(float)) {
    base = (float*)d_ws;
  } else {
    void* p = nullptr;
    hipGetSymbolAddress(&p, HIP_SYMBOL(g_ws));
    base = (float*)p;
  }
  float* P0 = base;          // x0 (seq, bf16, persists)
  float* PA = base + 1*NS;   // xseq(bf16) / ACT(bf16)
  float* PB = base + 2*NS;   // xt shortcut / xt2 / fmt2 re(bf16)
  float* PC = base + 3*NS;   // fmt1 re(bf16) / xt3 / xt4
  float* PD = base + 4*NS;   // d3-out(bf16) / QK(bf16) / fmt im(bf16)
  float* PF = base + 5*NS;   // d5-out(bf16) / CAT(bf16) / xss(bf16) / FFN(bf16)
  float* H0 = base + 6*NS;   // bf16 branch bufs
  float* H1 = H0 + NH;
  float* H2 = H1 + NH;
  float* WG = H2 + NH;                  // B*8*L2_
  float* ACC = WG + WGSLOT;             // 2304
  float* CW  = ACC + ACCSZ;             // fp32 weights
  bf16_t* CW16 = (bf16_t*)(CW + CWSZ);  // bf16 weight mirror
  int*   FLG = (int*)(CW + CWSZ + CW16SZF);

  static const int wsz[47] = {
    16384,128,128,128,1152,128,1024,8,8,8,1024,128,128,128,128,128,
    16384,128,1152,16384,128,3200,16384,128,4096,64,576,64,8192,128,
    576,64,16384,128,1152,128,128,128,512,4,512,128,16384,32768,128,128,128};
  int woff[47]; { int a = 0; for (int i = 0; i < 47; i++){ woff[i] = a; a += wsz[i]; } }
  const float* Wf[47]; for (int i = 0; i < 47; i++) Wf[i] = CW + woff[i];
  auto W16 = [&](int i){ return (const bf16_t*)(CW16 + woff[i] + (woff[i] >= W16SHIFT ? 4 : 0)); };
  const float *c1_b=Wf[1], *c1_g=Wf[2], *c1_be=Wf[3], *cpe1_w=Wf[4],
    *cpe1_b=Wf[5], *fw1=Wf[6], *fb1=Wf[7], *f_g=Wf[8], *f_be=Wf[9], *fw2=Wf[10],
    *fb2=Wf[11], *nbn_g=Wf[12], *nbn_be=Wf[13], *ln1_g=Wf[14], *ln1_b=Wf[15],
    *d3b1=Wf[17], *d3w2=Wf[18], *d5b1=Wf[20],
    *d5w2=Wf[21], *ap_b=Wf[23], *ip2_b=Wf[25],
    *dwc2_w=Wf[26], *dwc2_b=Wf[27], *qk_b=Wf[29], *lepe_w=Wf[30],
    *lepe_b=Wf[31], *op_b=Wf[33], *cpe2_w=Wf[34], *cpe2_b=Wf[35],
    *ln2_g=Wf[36], *ln2_b=Wf[37], *ffn_w1=Wf[38], *ffn_b1=Wf[39], *ffn_w2=Wf[40],
    *ffn_b2=Wf[41], *red_b=Wf[44], *red_g=Wf[45], *red_be=Wf[46];
  const bf16_t *c1_w16=W16(0), *d3w1_16=W16(16), *d5w1_16=W16(19), *ap_w16=W16(22),
    *ip2_w16=W16(24), *qk_w16=W16(28), *op_w16=W16(32), *red_w16=W16(43);

  const void* x = d_in[0];

  // 0. dtype probe + weight conversion (fp32 + bf16 mirror + fused po->red weight)
  k_probe<<<1, 256, 0, stream>>>((const bf16_t*)x, FLG);
  P47 ps; for (int i = 0; i < 47; i++) ps.p[i] = d_in[i+1];
  k_cvt<<<(TOTW+255)/256, 256, 0, stream>>>(ps, FLG, CW);
  k_cvt16<<<(TOTW+255)/256, 256, 0, stream>>>(CW, CW16);
  k_fuse_red<<<64, 256, 0, stream>>>(CW + WOFF_PO, CW + WOFF_RED,
                                     (bf16_t*)(CW16 + WOFF_RED + 4));

  dim3 tgrid(512, 4, 4), tblk(32, 8);

  // fully fused fmt, Hermitian half-spectrum pipeline (bf16 spectrum storage)
  auto fmt_fused = [&](const float* seq_in, bf16_t* re, bf16_t* im,
                       const float* add1, const bf16_t* add2, float* outp) {
    k_fft_row_fwd_half<<<1024, 256, 0, stream>>>(seq_in, re, im);
    k_fft_col_fwd_h<<<1024, 256, 0, stream>>>(re, im);
    k_freq1_h<<<132, 256, 0, stream>>>(re, fw1, fb1, f_g, f_be, WG);
    k_fft_col_inv_scaled_h<<<1024, 256, 0, stream>>>(re, im, WG, fw2, fb2);
    k_fft_row_inv_abs_seq_h<<<1024, 256, 0, stream>>>(re, im, nbn_g, nbn_be, add1, add2, outp);
  };

  auto attn = [&](const bf16_t* brin, float* qkbuf, int coff) {
    k_zero<<<9, 256, 0, stream>>>(ACC, 2304);
    k_mfma_tok<64,128,3,false,true,true><<<1024, 256, 0, stream>>>(brin, nullptr, qk_w16, qk_b, qkbuf);
    k_kv<<<1024, 256, 0, stream>>>((const bf16_t*)qkbuf, brin, ACC, ACC + B_*512);
    k_attn2<<<2048, 256, 0, stream>>>((const bf16_t*)qkbuf, brin, ACC, ACC + B_*512, lepe_w, lepe_b, (bf16_t*)PF, coff);
  };

  // x -> seq (bf16)                                        -> PA
  k_p2s<true><<<tgrid, tblk, 0, stream>>>(x, (bf16_t*)PA, FLG);
  // x_0 = relu(bn(conv1x1(x)))                             -> P0 (SEQ, bf16)
  k_mfma_c1<<<1024, 256, 0, stream>>>((const bf16_t*)PA, c1_w16, c1_b, c1_g, c1_be, (bf16_t*)P0);
  // xt = x + dw3(x,cpe1)+b  (bf16 in, fp32 out)            -> PB (shortcut)
  k_dw3<128,true><<<8192, 256, 0, stream>>>(PA, cpe1_w, cpe1_b, PB);
  // fused LN + {d3w1, d5w1, ap} GEMMs: xt -> PD(bf16), PF(bf16), PA(ACT bf16)
  k_mfma_ln3<<<1024, 256, 0, stream>>>(PB, ln1_g, ln1_b,
      d3w1_16, d3b1, d5w1_16, d5b1, ap_w16, ap_b,
      (bf16_t*)PD, (bf16_t*)PF, (bf16_t*)PA);
  // grouped convs consume PD/PF before attn reuses PF      -> H0/H1 (bf16)
  k_gconv<3><<<4096, 256, 0, stream>>>((const bf16_t*)PD, d3w2, (bf16_t*)H0);
  k_gconv<5><<<4096, 256, 0, stream>>>((const bf16_t*)PF, d5w2, (bf16_t*)H1);
  // branch3 -> attention -> CAT[:, :, 0:64] in PF (bf16)
  k_mfma_tok<64,64,1,false,true,true><<<1024, 256, 0, stream>>>((const bf16_t*)H0, nullptr, ip2_w16, ip2_b, (bf16_t*)H2);
  k_dw3h<<<4096, 256, 0, stream>>>((const bf16_t*)H2, dwc2_w, dwc2_b, (bf16_t*)H0);
  attn((const bf16_t*)H0, PD, 0);
  // branch5 -> attention -> CAT[:, :, 64:128]
  k_mfma_tok<64,64,1,false,true,true><<<1024, 256, 0, stream>>>((const bf16_t*)H1, nullptr, ip2_w16, ip2_b, (bf16_t*)H2);
  k_dw3h<<<4096, 256, 0, stream>>>((const bf16_t*)H2, dwc2_w, dwc2_b, (bf16_t*)H1);
  attn((const bf16_t*)H1, PD, 64);
  // xss = conv1x1(CAT * ACT, op_w)+op_b  (bf16 in/mul/out) -> PF (in-place)
  k_mfma_tok<128,128,1,true,true,true><<<1024, 256, 0, stream>>>(PF, (const bf16_t*)PA, op_w16, op_b, PF);
  // fmt1 (delayed) + xt2 = shortcut + xss + fmt1           -> PB
  fmt_fused(PB, (bf16_t*)PC, (bf16_t*)PD, PB, (const bf16_t*)PF, PB);
  // xt3 = xt2 + dw3(xt2,cpe2)+b  (fp32 in/out)             -> PC
  k_dw3<128,false><<<8192, 256, 0, stream>>>(PB, cpe2_w, cpe2_b, PC);
  // ffn(ln2(xt3))  (bf16 out)                              -> PF
  k_ln_ffn<<<16384, 256, 0, stream>>>(PC, ln2_g, ln2_b, ffn_w1, ffn_b1, ffn_w2, ffn_b2, (bf16_t*)PF);
  // fmt2 + xt4 = xt3 + ffn + fmt2                          -> PC
  fmt_fused(PC, (bf16_t*)PB, (bf16_t*)PD, PC, (const bf16_t*)PF, PC);
  // out = relu(bn(conv1x1([x0; po(xt4)], red_fused))) + x0 -> d_out (po folded into red)
  k_mfma_red<<<1024, 256, 0, stream>>>((const bf16_t*)P0, PC, red_w16, red_b, red_g, red_be, d_out, FLG);
}